// Round 3
// baseline (500.029 us; speedup 1.0000x reference)
//
#include <hip/hip_runtime.h>
#include <hip/hip_bf16.h>

// Problem constants
#define B_ 4
#define T_ 2048
#define E_ 1024
#define H_ 16
#define DH_ 64

typedef __bf16 bf16x8 __attribute__((ext_vector_type(8)));
typedef __bf16 bf16x4 __attribute__((ext_vector_type(4)));
typedef float f32x4 __attribute__((ext_vector_type(4)));

#define EXP2F(x) __builtin_amdgcn_exp2f(x)
#define NEG_INF (-__builtin_inff())

// ---------------------------------------------------------------- casts
__global__ void cast_f32_to_bf16(const float* __restrict__ src,
                                 __bf16* __restrict__ dst, int n) {
    int i = (blockIdx.x * blockDim.x + threadIdx.x) * 4;
    if (i + 3 < n) {
        float4 f = *reinterpret_cast<const float4*>(src + i);
        bf16x4 o = { (__bf16)f.x, (__bf16)f.y, (__bf16)f.z, (__bf16)f.w };
        *reinterpret_cast<bf16x4*>(dst + i) = o;
    }
}

// in: [H][E][DH] f32  ->  out: [H][DH][E] bf16  (so GEMM B-frags read contiguous K)
__global__ void cast_transpose_w(const float* __restrict__ src,
                                 __bf16* __restrict__ dst) {
    int idx = blockIdx.x * blockDim.x + threadIdx.x;  // over H*DH*E = 1048576
    int e = idx & (E_ - 1);
    int d = (idx >> 10) & (DH_ - 1);
    int h = idx >> 16;
    dst[idx] = (__bf16)src[(h * E_ + e) * DH_ + d];
}

// ---------------------------------------------------------------- GEMM (C = A * Bt^T)
// A: [M][K] bf16 row-major;  Bt: [N][K] bf16 row-major
// MODE 0: C[m][n] bf16    MODE 1: C[m][n] f32 + bias    MODE 2: C^T[n][m] bf16 (ldt = M stride)
#define BM 128
#define BN 64
#define BK 64

template<int MODE>
__global__ __launch_bounds__(256) void gemm_bt(
    const __bf16* __restrict__ A, const __bf16* __restrict__ Bt,
    void* __restrict__ Cout, const float* __restrict__ bias,
    int K, int N, long sA, long sB, long sC, int Hmod, int ldt) {

    __shared__ __bf16 As[BM][BK];
    __shared__ __bf16 Bs[BN][BK];

    int tid = threadIdx.x;
    int lane = tid & 63, wid = tid >> 6;
    int wr = wid >> 1, wc = wid & 1;
    int rlo = lane & 15, rhi = lane >> 4;

    int z = blockIdx.z;
    int bz = z / Hmod, hz = z % Hmod;
    const __bf16* Ab = A + (long)bz * sA + (long)blockIdx.x * BM * K;
    const __bf16* Bb = Bt + (long)hz * sB + (long)blockIdx.y * BN * K;

    f32x4 acc[4][2] = {};

    for (int k0 = 0; k0 < K; k0 += BK) {
        // stage A tile (128x64), XOR chunk-swizzled (chunk = 8 bf16 = 16B)
        #pragma unroll
        for (int p = 0; p < 4; p++) {
            int r = (tid >> 3) + p * 32;
            int c8 = (tid & 7) * 8;
            bf16x8 vv = *reinterpret_cast<const bf16x8*>(Ab + (long)r * K + k0 + c8);
            int cs = (c8 >> 3) ^ (r & 7);
            *reinterpret_cast<bf16x8*>(&As[r][cs * 8]) = vv;
        }
        // stage B tile (64x64)
        #pragma unroll
        for (int p = 0; p < 2; p++) {
            int r = (tid >> 3) + p * 32;
            int c8 = (tid & 7) * 8;
            bf16x8 vv = *reinterpret_cast<const bf16x8*>(Bb + (long)r * K + k0 + c8);
            int cs = (c8 >> 3) ^ (r & 7);
            *reinterpret_cast<bf16x8*>(&Bs[r][cs * 8]) = vv;
        }
        __syncthreads();

        #pragma unroll
        for (int kk = 0; kk < BK; kk += 32) {
            int ck = (kk + 8 * rhi) >> 3;
            bf16x8 af[4], bfr[2];
            #pragma unroll
            for (int mi = 0; mi < 4; mi++) {
                int r = wr * 64 + mi * 16 + rlo;
                af[mi] = *reinterpret_cast<const bf16x8*>(&As[r][(ck ^ (r & 7)) * 8]);
            }
            #pragma unroll
            for (int ni = 0; ni < 2; ni++) {
                int r = wc * 32 + ni * 16 + rlo;
                bfr[ni] = *reinterpret_cast<const bf16x8*>(&Bs[r][(ck ^ (r & 7)) * 8]);
            }
            #pragma unroll
            for (int mi = 0; mi < 4; mi++)
                #pragma unroll
                for (int ni = 0; ni < 2; ni++)
                    acc[mi][ni] = __builtin_amdgcn_mfma_f32_16x16x32_bf16(
                        af[mi], bfr[ni], acc[mi][ni], 0, 0, 0);
        }
        __syncthreads();
    }

    // epilogue: C row = 4*rhi + reg, col = rlo (verified gfx950 C/D layout)
    long rowbase = (long)blockIdx.x * BM + wr * 64;
    int colbase = blockIdx.y * BN + wc * 32;
    #pragma unroll
    for (int mi = 0; mi < 4; mi++) {
        #pragma unroll
        for (int ni = 0; ni < 2; ni++) {
            int cn = colbase + ni * 16 + rlo;
            if constexpr (MODE == 2) {
                // transposed write: Ct[cn][rm], 4 consecutive rm -> one bf16x4 store
                __bf16* C = (__bf16*)Cout + (long)z * sC;
                long rm = rowbase + mi * 16 + rhi * 4;
                bf16x4 o = { (__bf16)acc[mi][ni][0], (__bf16)acc[mi][ni][1],
                             (__bf16)acc[mi][ni][2], (__bf16)acc[mi][ni][3] };
                *reinterpret_cast<bf16x4*>(C + (long)cn * ldt + rm) = o;
            } else {
                #pragma unroll
                for (int r = 0; r < 4; r++) {
                    long rm = rowbase + mi * 16 + rhi * 4 + r;
                    if constexpr (MODE == 1) {
                        float* C = (float*)Cout + (long)z * sC;
                        C[rm * N + cn] = acc[mi][ni][r] + bias[cn];
                    } else {
                        __bf16* C = (__bf16*)Cout + (long)z * sC;
                        C[rm * N + cn] = (__bf16)acc[mi][ni][r];
                    }
                }
            }
        }
    }
}

// ---------------------------------------------------------------- attention
// grid (16, B*H); 256 threads = 4 waves. Block p handles q-tiles {31-p, p}
// (uniform 33 KV-step units/block). No __syncthreads: V^T read from global,
// P repack via per-wave LDS region only.
__global__ __launch_bounds__(256) void attn_kernel(
    const __bf16* __restrict__ q, const __bf16* __restrict__ k,
    const __bf16* __restrict__ vt, __bf16* __restrict__ attout) {

    __shared__ __bf16 Pl[4][16][64];    // per-wave P tile, chunk-swizzled

    int tid = threadIdx.x, lane = tid & 63, wid = tid >> 6;
    int rlo = lane & 15, rhi = lane >> 4;
    int bh = blockIdx.y;
    int b = bh >> 4, h = bh & 15;
    const __bf16* qb = q + (long)bh * T_ * DH_;
    const __bf16* kb = k + (long)bh * T_ * DH_;
    const __bf16* vtb = vt + (long)bh * T_ * DH_;   // [DH][T]

    // softmax in log2 domain: S_log2 = score * (1/8) * log2(e)
    const float SCL = 0.125f * 1.44269504088896340736f;

    #pragma unroll 1
    for (int ti = 0; ti < 2; ti++) {
        int tl = ti ? (int)blockIdx.x : 31 - (int)blockIdx.x;
        int q0 = tl * 64;

        // hoist Q fragments (2 d-ksteps)
        bf16x8 aq[2];
        {
            long qr = q0 + wid * 16 + rlo;
            aq[0] = *reinterpret_cast<const bf16x8*>(qb + qr * DH_ + 8 * rhi);
            aq[1] = *reinterpret_cast<const bf16x8*>(qb + qr * DH_ + 32 + 8 * rhi);
        }

        float m_[4], l_[4];
        f32x4 o[4] = {};
        #pragma unroll
        for (int r = 0; r < 4; r++) { m_[r] = NEG_INF; l_[r] = 0.f; }

        int ntiles = tl + 1;
        for (int t = 0; t < ntiles; t++) {
            int kt0 = t * 64;

            // S = (Q K^T) — K frags straight from global (L2-resident)
            f32x4 s[4];
            #pragma unroll
            for (int f = 0; f < 4; f++) {
                f32x4 accs = {};
                #pragma unroll
                for (int kk = 0; kk < 2; kk++) {
                    bf16x8 bk = *reinterpret_cast<const bf16x8*>(
                        kb + (long)(kt0 + f * 16 + rlo) * DH_ + kk * 32 + 8 * rhi);
                    accs = __builtin_amdgcn_mfma_f32_16x16x32_bf16(aq[kk], bk, accs, 0, 0, 0);
                }
                s[f] = accs;
            }

            // scale (log2 domain) + causal mask (diagonal tile only)
            bool diag = (kt0 == q0);
            #pragma unroll
            for (int f = 0; f < 4; f++) {
                int kcol = kt0 + f * 16 + rlo;
                #pragma unroll
                for (int r = 0; r < 4; r++) {
                    float sv = s[f][r] * SCL;
                    if (diag) {
                        int qrow = q0 + wid * 16 + rhi * 4 + r;
                        if (kcol > qrow) sv = NEG_INF;
                    }
                    s[f][r] = sv;
                }
            }

            // online softmax (row stats replicated across each 16-lane group)
            float so[4];
            #pragma unroll
            for (int r = 0; r < 4; r++) {
                float pm = fmaxf(fmaxf(s[0][r], s[1][r]), fmaxf(s[2][r], s[3][r]));
                pm = fmaxf(pm, __shfl_xor(pm, 1));
                pm = fmaxf(pm, __shfl_xor(pm, 2));
                pm = fmaxf(pm, __shfl_xor(pm, 4));
                pm = fmaxf(pm, __shfl_xor(pm, 8));
                float nm = fmaxf(m_[r], pm);
                so[r] = EXP2F(m_[r] - nm);
                float rsum = 0.f;
                #pragma unroll
                for (int f = 0; f < 4; f++) {
                    float p = EXP2F(s[f][r] - nm);
                    s[f][r] = p;
                    rsum += p;
                }
                rsum += __shfl_xor(rsum, 1);
                rsum += __shfl_xor(rsum, 2);
                rsum += __shfl_xor(rsum, 4);
                rsum += __shfl_xor(rsum, 8);
                l_[r] = l_[r] * so[r] + rsum;
                m_[r] = nm;
            }
            #pragma unroll
            for (int fd = 0; fd < 4; fd++)
                #pragma unroll
                for (int r = 0; r < 4; r++)
                    o[fd][r] *= so[r];

            // P -> bf16 -> per-wave LDS (swizzled); same-wave RAW, no barrier
            #pragma unroll
            for (int f = 0; f < 4; f++) {
                int col = f * 16 + rlo;
                #pragma unroll
                for (int r = 0; r < 4; r++) {
                    int row = rhi * 4 + r;
                    Pl[wid][row][(((col >> 3) ^ (row & 7)) << 3) + (col & 7)] = (__bf16)s[f][r];
                }
            }

            // O += P V  (V^T frags straight from global vt[d][t])
            #pragma unroll
            for (int kk = 0; kk < 2; kk++) {
                int ck = kk * 4 + rhi;
                bf16x8 ap = *reinterpret_cast<const bf16x8*>(&Pl[wid][rlo][(ck ^ (rlo & 7)) * 8]);
                #pragma unroll
                for (int fd = 0; fd < 4; fd++) {
                    bf16x8 bv = *reinterpret_cast<const bf16x8*>(
                        vtb + (long)(fd * 16 + rlo) * T_ + kt0 + kk * 32 + 8 * rhi);
                    o[fd] = __builtin_amdgcn_mfma_f32_16x16x32_bf16(ap, bv, o[fd], 0, 0, 0);
                }
            }
        }

        // normalize + write attout[b*T + qrow][h*64 + d]
        #pragma unroll
        for (int r = 0; r < 4; r++) {
            float inv = 1.f / l_[r];
            long qrow = q0 + wid * 16 + rhi * 4 + r;
            #pragma unroll
            for (int fd = 0; fd < 4; fd++) {
                int d = fd * 16 + rlo;
                attout[((long)b * T_ + qrow) * E_ + h * DH_ + d] = (__bf16)(o[fd][r] * inv);
            }
        }
    }
}

// ---------------------------------------------------------------- launcher
extern "C" void kernel_launch(void* const* d_in, const int* in_sizes, int n_in,
                              void* d_out, int out_size, void* d_ws, size_t ws_size,
                              hipStream_t stream) {
    const float* x  = (const float*)d_in[0];
    const float* Wq = (const float*)d_in[1];
    const float* Wk = (const float*)d_in[2];
    const float* Wv = (const float*)d_in[3];
    const float* Wp = (const float*)d_in[4];
    const float* bp = (const float*)d_in[5];

    char* ws = (char*)d_ws;
    const long SZ_XE = (long)B_ * T_ * E_ * 2;      // 16 MB (bf16 [B*T][E])
    const long SZ_W  = (long)H_ * DH_ * E_ * 2;     // 2 MB
    __bf16* xb  = (__bf16*)(ws);                    // x bf16; REUSED as attout after QKV
    __bf16* qb  = (__bf16*)(ws + SZ_XE);
    __bf16* kb  = (__bf16*)(ws + 2 * SZ_XE);
    __bf16* vt  = (__bf16*)(ws + 3 * SZ_XE);        // V^T: [B*H][DH][T]
    __bf16* wqt = (__bf16*)(ws + 4 * SZ_XE);
    __bf16* wkt = (__bf16*)(ws + 4 * SZ_XE + SZ_W);
    __bf16* wvt = (__bf16*)(ws + 4 * SZ_XE + 2 * SZ_W);
    __bf16* wpb = (__bf16*)(ws + 4 * SZ_XE + 3 * SZ_W);
    __bf16* att = xb;  // alias: xb dead after QKV GEMMs (stream-ordered)

    // casts
    cast_f32_to_bf16<<<8192, 256, 0, stream>>>(x, xb, B_ * T_ * E_);
    cast_transpose_w<<<4096, 256, 0, stream>>>(Wq, wqt);
    cast_transpose_w<<<4096, 256, 0, stream>>>(Wk, wkt);
    cast_transpose_w<<<4096, 256, 0, stream>>>(Wv, wvt);
    cast_f32_to_bf16<<<1024, 256, 0, stream>>>(Wp, wpb, E_ * E_);

    // QKV projections: per z=(b*H+h): C[T][DH] = X_b[T][E] @ W_h[DH][E]^T
    long sA = (long)T_ * E_, sB = (long)DH_ * E_, sC = (long)T_ * DH_;
    gemm_bt<0><<<dim3(T_ / BM, 1, B_ * H_), 256, 0, stream>>>(
        xb, wqt, qb, nullptr, E_, DH_, sA, sB, sC, H_, 0);
    gemm_bt<0><<<dim3(T_ / BM, 1, B_ * H_), 256, 0, stream>>>(
        xb, wkt, kb, nullptr, E_, DH_, sA, sB, sC, H_, 0);
    // V projection writes V^T directly: vt[bh][d][t]
    gemm_bt<2><<<dim3(T_ / BM, 1, B_ * H_), 256, 0, stream>>>(
        xb, wvt, vt, nullptr, E_, DH_, sA, sB, sC, H_, T_);

    // causal attention (paired q-tiles, uniform work)
    attn_kernel<<<dim3(16, B_ * H_), 256, 0, stream>>>(qb, kb, vt, att);

    // output projection + bias (fp32 out)
    gemm_bt<1><<<dim3((B_ * T_) / BM, E_ / BN, 1), 256, 0, stream>>>(
        att, wpb, (float*)d_out, bp, E_, E_, 0, 0, 0, 1, 0);
}

// Round 4
// 268.535 us; speedup vs baseline: 1.8621x; 1.8621x over previous
//
#include <hip/hip_runtime.h>
#include <hip/hip_bf16.h>

// Problem constants
#define B_ 4
#define T_ 2048
#define E_ 1024
#define H_ 16
#define DH_ 64

typedef __bf16 bf16x8 __attribute__((ext_vector_type(8)));
typedef __bf16 bf16x4 __attribute__((ext_vector_type(4)));
typedef float f32x4 __attribute__((ext_vector_type(4)));

#define EXP2F(x) __builtin_amdgcn_exp2f(x)
#define NEG_INF (-__builtin_inff())

// async global->LDS, 16B per lane: lane l writes lds_base + l*16
__device__ __forceinline__ void async_copy16(const __bf16* g, __bf16* l) {
    __builtin_amdgcn_global_load_lds(
        (const __attribute__((address_space(1))) unsigned int*)g,
        (__attribute__((address_space(3))) unsigned int*)l, 16, 0, 0);
}

// ---------------------------------------------------------------- casts
__global__ void cast_f32_to_bf16(const float* __restrict__ src,
                                 __bf16* __restrict__ dst, int n) {
    int i = (blockIdx.x * blockDim.x + threadIdx.x) * 4;
    if (i + 3 < n) {
        float4 f = *reinterpret_cast<const float4*>(src + i);
        bf16x4 o = { (__bf16)f.x, (__bf16)f.y, (__bf16)f.z, (__bf16)f.w };
        *reinterpret_cast<bf16x4*>(dst + i) = o;
    }
}

// in: [H][E][DH] f32  ->  out: [H][DH][E] bf16
__global__ void cast_transpose_w(const float* __restrict__ src,
                                 __bf16* __restrict__ dst) {
    int idx = blockIdx.x * blockDim.x + threadIdx.x;  // over H*DH*E = 1048576
    int e = idx & (E_ - 1);
    int d = (idx >> 10) & (DH_ - 1);
    int h = idx >> 16;
    dst[idx] = (__bf16)src[(h * E_ + e) * DH_ + d];
}

// ---------------------------------------------------------------- GEMM (C = A * Bt^T)
// MODE 0: C[m][n] bf16   MODE 1: C[m][n] f32 + bias   MODE 2: C^T[n][m] bf16 (ldt = M stride)
#define BM 128
#define BN 64
#define BK 64

template<int MODE>
__global__ __launch_bounds__(256) void gemm_bt(
    const __bf16* __restrict__ A, const __bf16* __restrict__ Bt,
    void* __restrict__ Cout, const float* __restrict__ bias,
    int K, int N, long sA, long sB, long sC, int Hmod, int ldt) {

    __shared__ __bf16 As[BM][BK];
    __shared__ __bf16 Bs[BN][BK];

    int tid = threadIdx.x;
    int lane = tid & 63, wid = tid >> 6;
    int wr = wid >> 1, wc = wid & 1;
    int rlo = lane & 15, rhi = lane >> 4;

    int z = blockIdx.z;
    int bz = z / Hmod, hz = z % Hmod;
    const __bf16* Ab = A + (long)bz * sA + (long)blockIdx.x * BM * K;
    const __bf16* Bb = Bt + (long)hz * sB + (long)blockIdx.y * BN * K;

    f32x4 acc[4][2] = {};

    for (int k0 = 0; k0 < K; k0 += BK) {
        #pragma unroll
        for (int p = 0; p < 4; p++) {
            int r = (tid >> 3) + p * 32;
            int c8 = (tid & 7) * 8;
            bf16x8 vv = *reinterpret_cast<const bf16x8*>(Ab + (long)r * K + k0 + c8);
            int cs = (c8 >> 3) ^ (r & 7);
            *reinterpret_cast<bf16x8*>(&As[r][cs * 8]) = vv;
        }
        #pragma unroll
        for (int p = 0; p < 2; p++) {
            int r = (tid >> 3) + p * 32;
            int c8 = (tid & 7) * 8;
            bf16x8 vv = *reinterpret_cast<const bf16x8*>(Bb + (long)r * K + k0 + c8);
            int cs = (c8 >> 3) ^ (r & 7);
            *reinterpret_cast<bf16x8*>(&Bs[r][cs * 8]) = vv;
        }
        __syncthreads();

        #pragma unroll
        for (int kk = 0; kk < BK; kk += 32) {
            int ck = (kk + 8 * rhi) >> 3;
            bf16x8 af[4], bfr[2];
            #pragma unroll
            for (int mi = 0; mi < 4; mi++) {
                int r = wr * 64 + mi * 16 + rlo;
                af[mi] = *reinterpret_cast<const bf16x8*>(&As[r][(ck ^ (r & 7)) * 8]);
            }
            #pragma unroll
            for (int ni = 0; ni < 2; ni++) {
                int r = wc * 32 + ni * 16 + rlo;
                bfr[ni] = *reinterpret_cast<const bf16x8*>(&Bs[r][(ck ^ (r & 7)) * 8]);
            }
            #pragma unroll
            for (int mi = 0; mi < 4; mi++)
                #pragma unroll
                for (int ni = 0; ni < 2; ni++)
                    acc[mi][ni] = __builtin_amdgcn_mfma_f32_16x16x32_bf16(
                        af[mi], bfr[ni], acc[mi][ni], 0, 0, 0);
        }
        __syncthreads();
    }

    long rowbase = (long)blockIdx.x * BM + wr * 64;
    int colbase = blockIdx.y * BN + wc * 32;
    #pragma unroll
    for (int mi = 0; mi < 4; mi++) {
        #pragma unroll
        for (int ni = 0; ni < 2; ni++) {
            int cn = colbase + ni * 16 + rlo;
            if constexpr (MODE == 2) {
                __bf16* C = (__bf16*)Cout + (long)z * sC;
                long rm = rowbase + mi * 16 + rhi * 4;
                bf16x4 o = { (__bf16)acc[mi][ni][0], (__bf16)acc[mi][ni][1],
                             (__bf16)acc[mi][ni][2], (__bf16)acc[mi][ni][3] };
                *reinterpret_cast<bf16x4*>(C + (long)cn * ldt + rm) = o;
            } else {
                #pragma unroll
                for (int r = 0; r < 4; r++) {
                    long rm = rowbase + mi * 16 + rhi * 4 + r;
                    if constexpr (MODE == 1) {
                        float* C = (float*)Cout + (long)z * sC;
                        C[rm * N + cn] = acc[mi][ni][r] + bias[cn];
                    } else {
                        __bf16* C = (__bf16*)Cout + (long)z * sC;
                        C[rm * N + cn] = (__bf16)acc[mi][ni][r];
                    }
                }
            }
        }
    }
}

// ---------------------------------------------------------------- attention
// grid (16, 64); 256 threads = 4 waves. Flat block id fid remapped so each
// (b,h)'s 16 blocks land on ONE XCD (L2 residence for its 512KB K+V).
// Block handles q-tiles {31-p, p} fused over one KV sweep (tile p's KV range
// is a subset). K and V^T tiles double-buffered in LDS via global_load_lds
// with pre-swizzled global source (XOR chunk swizzle), staged 1 step ahead.
__global__ __launch_bounds__(256) void attn_kernel(
    const __bf16* __restrict__ q, const __bf16* __restrict__ k,
    const __bf16* __restrict__ vt, __bf16* __restrict__ attout) {

    __shared__ __bf16 Ks[2][64][64];
    __shared__ __bf16 Vs[2][64][64];
    __shared__ __bf16 Pl[4][16][64];

    int tid = threadIdx.x, lane = tid & 63, wid = tid >> 6;
    int rlo = lane & 15, rhi = lane >> 4;

    int fid = blockIdx.y * 16 + blockIdx.x;
    int xcd = fid & 7, slot = fid >> 3;     // round-robin XCD assumption (perf-only)
    int bh = xcd * 8 + (slot >> 4);         // 8 bh per XCD
    int p = slot & 15;
    int tA = 31 - p, tB = p;                // q-tile indices (64-row tiles)

    int b = bh >> 4, h = bh & 15;
    const __bf16* qb = q + (long)bh * T_ * DH_;
    const __bf16* kb = k + (long)bh * T_ * DH_;
    const __bf16* vtb = vt + (long)bh * T_ * DH_;   // [DH][T]

    const float SCL = 0.125f * 1.44269504088896340736f;  // 1/8 * log2(e)

    // staging geometry: wave w stages rows [w*16, w*16+16), 2 instrs of 8 rows.
    // lane l -> row srow(+8), chunk (l&7); content = global chunk (l&7)^(row&7)
    int srow = wid * 16 + (lane >> 3);          // (srow+8)&7 == srow&7
    int sc0 = (lane & 7) ^ (srow & 7);

    // Q fragments for both tiles
    bf16x8 aqA[2], aqB[2];
    {
        long qrA = (long)tA * 64 + wid * 16 + rlo;
        aqA[0] = *reinterpret_cast<const bf16x8*>(qb + qrA * DH_ + 8 * rhi);
        aqA[1] = *reinterpret_cast<const bf16x8*>(qb + qrA * DH_ + 32 + 8 * rhi);
        long qrB = (long)tB * 64 + wid * 16 + rlo;
        aqB[0] = *reinterpret_cast<const bf16x8*>(qb + qrB * DH_ + 8 * rhi);
        aqB[1] = *reinterpret_cast<const bf16x8*>(qb + qrB * DH_ + 32 + 8 * rhi);
    }

    float mA[4], lA[4], mB[4], lB[4];
    f32x4 oA[4] = {}, oB[4] = {};
    #pragma unroll
    for (int r = 0; r < 4; r++) { mA[r] = NEG_INF; lA[r] = 0.f; mB[r] = NEG_INF; lB[r] = 0.f; }

    auto STAGE = [&](int bs, int t) {
        const __bf16* ksrc = kb + (long)(t * 64 + srow) * DH_ + sc0 * 8;
        async_copy16(ksrc,           &Ks[bs][wid * 16][0]);
        async_copy16(ksrc + 8 * DH_, &Ks[bs][wid * 16 + 8][0]);
        const __bf16* vsrc = vtb + (long)srow * T_ + t * 64 + sc0 * 8;
        async_copy16(vsrc,           &Vs[bs][wid * 16][0]);
        async_copy16(vsrc + 8 * T_,  &Vs[bs][wid * 16 + 8][0]);
    };

    auto PROCESS = [&](int bs, int t, int tq, bf16x8* aq, float* m_, float* l_, f32x4* o) {
        int kt0 = t * 64;
        // S = Q K^T from LDS
        f32x4 s[4];
        #pragma unroll
        for (int f = 0; f < 4; f++) {
            f32x4 accs = {};
            int r = f * 16 + rlo;
            #pragma unroll
            for (int kk = 0; kk < 2; kk++) {
                bf16x8 bk = *reinterpret_cast<const bf16x8*>(
                    &Ks[bs][r][((kk * 4 + rhi) ^ (r & 7)) * 8]);
                accs = __builtin_amdgcn_mfma_f32_16x16x32_bf16(aq[kk], bk, accs, 0, 0, 0);
            }
            s[f] = accs;
        }

        // scale (log2 domain) + causal mask (diagonal tile only)
        bool diag = (t == tq);
        #pragma unroll
        for (int f = 0; f < 4; f++) {
            int kcol = kt0 + f * 16 + rlo;
            #pragma unroll
            for (int r = 0; r < 4; r++) {
                float sv = s[f][r] * SCL;
                if (diag) {
                    int qrow = tq * 64 + wid * 16 + rhi * 4 + r;
                    if (kcol > qrow) sv = NEG_INF;
                }
                s[f][r] = sv;
            }
        }

        // online softmax (row stats replicated across 16-lane groups)
        float so[4];
        #pragma unroll
        for (int r = 0; r < 4; r++) {
            float pm = fmaxf(fmaxf(s[0][r], s[1][r]), fmaxf(s[2][r], s[3][r]));
            pm = fmaxf(pm, __shfl_xor(pm, 1));
            pm = fmaxf(pm, __shfl_xor(pm, 2));
            pm = fmaxf(pm, __shfl_xor(pm, 4));
            pm = fmaxf(pm, __shfl_xor(pm, 8));
            float nm = fmaxf(m_[r], pm);
            so[r] = EXP2F(m_[r] - nm);
            float rsum = 0.f;
            #pragma unroll
            for (int f = 0; f < 4; f++) {
                float pv = EXP2F(s[f][r] - nm);
                s[f][r] = pv;
                rsum += pv;
            }
            rsum += __shfl_xor(rsum, 1);
            rsum += __shfl_xor(rsum, 2);
            rsum += __shfl_xor(rsum, 4);
            rsum += __shfl_xor(rsum, 8);
            l_[r] = l_[r] * so[r] + rsum;
            m_[r] = nm;
        }
        #pragma unroll
        for (int fd = 0; fd < 4; fd++)
            #pragma unroll
            for (int r = 0; r < 4; r++)
                o[fd][r] *= so[r];

        // P -> bf16 -> per-wave LDS (swizzled); same-wave RAW
        #pragma unroll
        for (int f = 0; f < 4; f++) {
            int col = f * 16 + rlo;
            #pragma unroll
            for (int r = 0; r < 4; r++) {
                int row = rhi * 4 + r;
                Pl[wid][row][(((col >> 3) ^ (row & 7)) << 3) + (col & 7)] = (__bf16)s[f][r];
            }
        }

        // O += P V  (V^T frags from LDS)
        #pragma unroll
        for (int kk = 0; kk < 2; kk++) {
            int ck = kk * 4 + rhi;
            bf16x8 ap = *reinterpret_cast<const bf16x8*>(&Pl[wid][rlo][(ck ^ (rlo & 7)) * 8]);
            #pragma unroll
            for (int fd = 0; fd < 4; fd++) {
                int vr = fd * 16 + rlo;
                bf16x8 bv = *reinterpret_cast<const bf16x8*>(
                    &Vs[bs][vr][(ck ^ (vr & 7)) * 8]);
                o[fd] = __builtin_amdgcn_mfma_f32_16x16x32_bf16(ap, bv, o[fd], 0, 0, 0);
            }
        }
    };

    int nsteps = tA + 1;
    STAGE(0, 0);
    __syncthreads();

    for (int t = 0; t < nsteps; ++t) {
        int cur = t & 1;
        if (t + 1 < nsteps) STAGE(cur ^ 1, t + 1);   // prefetch next tile
        PROCESS(cur, t, tA, aqA, mA, lA, oA);
        if (t <= tB) PROCESS(cur, t, tB, aqB, mB, lB, oB);
        __syncthreads();   // drains vmcnt (prefetch done) + WAR on buffers
    }

    // epilogue: normalize + write both q-tiles
    #pragma unroll
    for (int r = 0; r < 4; r++) {
        float invA = 1.f / lA[r];
        float invB = 1.f / lB[r];
        long qrA = (long)tA * 64 + wid * 16 + rhi * 4 + r;
        long qrB = (long)tB * 64 + wid * 16 + rhi * 4 + r;
        #pragma unroll
        for (int fd = 0; fd < 4; fd++) {
            int d = fd * 16 + rlo;
            attout[((long)b * T_ + qrA) * E_ + h * DH_ + d] = (__bf16)(oA[fd][r] * invA);
            attout[((long)b * T_ + qrB) * E_ + h * DH_ + d] = (__bf16)(oB[fd][r] * invB);
        }
    }
}

// ---------------------------------------------------------------- launcher
extern "C" void kernel_launch(void* const* d_in, const int* in_sizes, int n_in,
                              void* d_out, int out_size, void* d_ws, size_t ws_size,
                              hipStream_t stream) {
    const float* x  = (const float*)d_in[0];
    const float* Wq = (const float*)d_in[1];
    const float* Wk = (const float*)d_in[2];
    const float* Wv = (const float*)d_in[3];
    const float* Wp = (const float*)d_in[4];
    const float* bp = (const float*)d_in[5];

    char* ws = (char*)d_ws;
    const long SZ_XE = (long)B_ * T_ * E_ * 2;      // 16 MB (bf16 [B*T][E])
    const long SZ_W  = (long)H_ * DH_ * E_ * 2;     // 2 MB
    __bf16* xb  = (__bf16*)(ws);                    // x bf16; REUSED as attout after QKV
    __bf16* qb  = (__bf16*)(ws + SZ_XE);
    __bf16* kb  = (__bf16*)(ws + 2 * SZ_XE);
    __bf16* vt  = (__bf16*)(ws + 3 * SZ_XE);        // V^T: [B*H][DH][T]
    __bf16* wqt = (__bf16*)(ws + 4 * SZ_XE);
    __bf16* wkt = (__bf16*)(ws + 4 * SZ_XE + SZ_W);
    __bf16* wvt = (__bf16*)(ws + 4 * SZ_XE + 2 * SZ_W);
    __bf16* wpb = (__bf16*)(ws + 4 * SZ_XE + 3 * SZ_W);
    __bf16* att = xb;  // alias: xb dead after QKV GEMMs (stream-ordered)

    // casts
    cast_f32_to_bf16<<<8192, 256, 0, stream>>>(x, xb, B_ * T_ * E_);
    cast_transpose_w<<<4096, 256, 0, stream>>>(Wq, wqt);
    cast_transpose_w<<<4096, 256, 0, stream>>>(Wk, wkt);
    cast_transpose_w<<<4096, 256, 0, stream>>>(Wv, wvt);
    cast_f32_to_bf16<<<1024, 256, 0, stream>>>(Wp, wpb, E_ * E_);

    // QKV projections: per z=(b*H+h): C[T][DH] = X_b[T][E] @ W_h[DH][E]^T
    long sA = (long)T_ * E_, sB = (long)DH_ * E_, sC = (long)T_ * DH_;
    gemm_bt<0><<<dim3(T_ / BM, 1, B_ * H_), 256, 0, stream>>>(
        xb, wqt, qb, nullptr, E_, DH_, sA, sB, sC, H_, 0);
    gemm_bt<0><<<dim3(T_ / BM, 1, B_ * H_), 256, 0, stream>>>(
        xb, wkt, kb, nullptr, E_, DH_, sA, sB, sC, H_, 0);
    // V projection writes V^T directly: vt[bh][d][t]
    gemm_bt<2><<<dim3(T_ / BM, 1, B_ * H_), 256, 0, stream>>>(
        xb, wvt, vt, nullptr, E_, DH_, sA, sB, sC, H_, T_);

    // causal attention (fused paired q-tiles, double-buffered LDS staging)
    attn_kernel<<<dim3(16, B_ * H_), 256, 0, stream>>>(qb, kb, vt, att);

    // output projection + bias (fp32 out)
    gemm_bt<1><<<dim3((B_ * T_) / BM, E_ / BN, 1), 256, 0, stream>>>(
        att, wpb, (float*)d_out, bp, E_, E_, 0, 0, 0, 1, 0);
}

// Round 5
// 233.381 us; speedup vs baseline: 2.1425x; 1.1506x over previous
//
#include <hip/hip_runtime.h>
#include <hip/hip_bf16.h>

// Problem constants
#define B_ 4
#define T_ 2048
#define E_ 1024
#define H_ 16
#define DH_ 64

typedef __bf16 bf16x8 __attribute__((ext_vector_type(8)));
typedef __bf16 bf16x4 __attribute__((ext_vector_type(4)));
typedef float f32x4 __attribute__((ext_vector_type(4)));

#define EXP2F(x) __builtin_amdgcn_exp2f(x)
#define NEG_INF (-__builtin_inff())

// async global->LDS, 16B per lane: lane l writes lds_base + l*16
__device__ __forceinline__ void async_copy16(const __bf16* g, __bf16* l) {
    __builtin_amdgcn_global_load_lds(
        (const __attribute__((address_space(1))) unsigned int*)g,
        (__attribute__((address_space(3))) unsigned int*)l, 16, 0, 0);
}

// ---------------------------------------------------------------- casts
__global__ void cast_f32_to_bf16(const float* __restrict__ src,
                                 __bf16* __restrict__ dst, int n) {
    int i = (blockIdx.x * blockDim.x + threadIdx.x) * 4;
    if (i + 3 < n) {
        float4 f = *reinterpret_cast<const float4*>(src + i);
        bf16x4 o = { (__bf16)f.x, (__bf16)f.y, (__bf16)f.z, (__bf16)f.w };
        *reinterpret_cast<bf16x4*>(dst + i) = o;
    }
}

// in: [H][E][DH] f32  ->  out: [H][DH][E] bf16
__global__ void cast_transpose_w(const float* __restrict__ src,
                                 __bf16* __restrict__ dst) {
    int idx = blockIdx.x * blockDim.x + threadIdx.x;  // over H*DH*E = 1048576
    int e = idx & (E_ - 1);
    int d = (idx >> 10) & (DH_ - 1);
    int h = idx >> 16;
    dst[idx] = (__bf16)src[(h * E_ + e) * DH_ + d];
}

// ---------------------------------------------------------------- GEMM (C = A * Bt^T)
// MODE 0: C[m][n] bf16   MODE 1: C[m][n] f32 + bias   MODE 2: C^T[n][m] bf16 (ldt = M stride)
#define BM 128
#define BN 64
#define BK 64

template<int MODE>
__global__ __launch_bounds__(256) void gemm_bt(
    const __bf16* __restrict__ A, const __bf16* __restrict__ Bt,
    void* __restrict__ Cout, const float* __restrict__ bias,
    int K, int N, long sA, long sB, long sC, int Hmod, int ldt) {

    __shared__ __bf16 As[BM][BK];
    __shared__ __bf16 Bs[BN][BK];

    int tid = threadIdx.x;
    int lane = tid & 63, wid = tid >> 6;
    int wr = wid >> 1, wc = wid & 1;
    int rlo = lane & 15, rhi = lane >> 4;

    int z = blockIdx.z;
    int bz = z / Hmod, hz = z % Hmod;
    const __bf16* Ab = A + (long)bz * sA + (long)blockIdx.x * BM * K;
    const __bf16* Bb = Bt + (long)hz * sB + (long)blockIdx.y * BN * K;

    f32x4 acc[4][2] = {};

    for (int k0 = 0; k0 < K; k0 += BK) {
        #pragma unroll
        for (int p = 0; p < 4; p++) {
            int r = (tid >> 3) + p * 32;
            int c8 = (tid & 7) * 8;
            bf16x8 vv = *reinterpret_cast<const bf16x8*>(Ab + (long)r * K + k0 + c8);
            int cs = (c8 >> 3) ^ (r & 7);
            *reinterpret_cast<bf16x8*>(&As[r][cs * 8]) = vv;
        }
        #pragma unroll
        for (int p = 0; p < 2; p++) {
            int r = (tid >> 3) + p * 32;
            int c8 = (tid & 7) * 8;
            bf16x8 vv = *reinterpret_cast<const bf16x8*>(Bb + (long)r * K + k0 + c8);
            int cs = (c8 >> 3) ^ (r & 7);
            *reinterpret_cast<bf16x8*>(&Bs[r][cs * 8]) = vv;
        }
        __syncthreads();

        #pragma unroll
        for (int kk = 0; kk < BK; kk += 32) {
            int ck = (kk + 8 * rhi) >> 3;
            bf16x8 af[4], bfr[2];
            #pragma unroll
            for (int mi = 0; mi < 4; mi++) {
                int r = wr * 64 + mi * 16 + rlo;
                af[mi] = *reinterpret_cast<const bf16x8*>(&As[r][(ck ^ (r & 7)) * 8]);
            }
            #pragma unroll
            for (int ni = 0; ni < 2; ni++) {
                int r = wc * 32 + ni * 16 + rlo;
                bfr[ni] = *reinterpret_cast<const bf16x8*>(&Bs[r][(ck ^ (r & 7)) * 8]);
            }
            #pragma unroll
            for (int mi = 0; mi < 4; mi++)
                #pragma unroll
                for (int ni = 0; ni < 2; ni++)
                    acc[mi][ni] = __builtin_amdgcn_mfma_f32_16x16x32_bf16(
                        af[mi], bfr[ni], acc[mi][ni], 0, 0, 0);
        }
        __syncthreads();
    }

    long rowbase = (long)blockIdx.x * BM + wr * 64;
    int colbase = blockIdx.y * BN + wc * 32;
    #pragma unroll
    for (int mi = 0; mi < 4; mi++) {
        #pragma unroll
        for (int ni = 0; ni < 2; ni++) {
            int cn = colbase + ni * 16 + rlo;
            if constexpr (MODE == 2) {
                __bf16* C = (__bf16*)Cout + (long)z * sC;
                long rm = rowbase + mi * 16 + rhi * 4;
                bf16x4 o = { (__bf16)acc[mi][ni][0], (__bf16)acc[mi][ni][1],
                             (__bf16)acc[mi][ni][2], (__bf16)acc[mi][ni][3] };
                *reinterpret_cast<bf16x4*>(C + (long)cn * ldt + rm) = o;
            } else {
                #pragma unroll
                for (int r = 0; r < 4; r++) {
                    long rm = rowbase + mi * 16 + rhi * 4 + r;
                    if constexpr (MODE == 1) {
                        float* C = (float*)Cout + (long)z * sC;
                        C[rm * N + cn] = acc[mi][ni][r] + bias[cn];
                    } else {
                        __bf16* C = (__bf16*)Cout + (long)z * sC;
                        C[rm * N + cn] = (__bf16)acc[mi][ni][r];
                    }
                }
            }
        }
    }
}

// ---------------------------------------------------------------- attention
// grid (16, 64); 256 threads = 4 waves. fid remapped so each (b,h)'s 16
// blocks land on ONE XCD. Block handles q-tiles {31-p, p} fused over one KV
// sweep. K/V^T double-buffered LDS via global_load_lds (pre-swizzled src).
// SWAPPED QK^T: s = mfma(K,Q) -> lane holds 16 S-values of q-row (lane&15);
// softmax is in-lane tree + 2 shuffles; m/l scalar; P packed as b64 writes.
__global__ __launch_bounds__(256) void attn_kernel(
    const __bf16* __restrict__ q, const __bf16* __restrict__ k,
    const __bf16* __restrict__ vt, __bf16* __restrict__ attout) {

    __shared__ __bf16 Ks[2][64][64];
    __shared__ __bf16 Vs[2][64][64];
    __shared__ __bf16 Pl[4][16][64];

    int tid = threadIdx.x, lane = tid & 63, wid = tid >> 6;
    int rlo = lane & 15, rhi = lane >> 4;

    int fid = blockIdx.y * 16 + blockIdx.x;
    int xcd = fid & 7, slot = fid >> 3;     // round-robin XCD assumption (perf-only)
    int bh = xcd * 8 + (slot >> 4);         // 8 bh per XCD
    int p = slot & 15;
    int tA = 31 - p, tB = p;                // q-tile indices (64-row tiles)

    int b = bh >> 4, h = bh & 15;
    const __bf16* qb = q + (long)bh * T_ * DH_;
    const __bf16* kb = k + (long)bh * T_ * DH_;
    const __bf16* vtb = vt + (long)bh * T_ * DH_;   // [DH][T]

    const float SCL = 0.125f * 1.44269504088896340736f;  // 1/8 * log2(e)

    // staging geometry (pre-swizzled global source, linear LDS dest)
    int srow = wid * 16 + (lane >> 3);
    int sc0 = (lane & 7) ^ (srow & 7);

    // Q fragments for both tiles (lane rlo = q row; rhi = d-chunk)
    bf16x8 aqA[2], aqB[2];
    {
        long qrA = (long)tA * 64 + wid * 16 + rlo;
        aqA[0] = *reinterpret_cast<const bf16x8*>(qb + qrA * DH_ + 8 * rhi);
        aqA[1] = *reinterpret_cast<const bf16x8*>(qb + qrA * DH_ + 32 + 8 * rhi);
        long qrB = (long)tB * 64 + wid * 16 + rlo;
        aqB[0] = *reinterpret_cast<const bf16x8*>(qb + qrB * DH_ + 8 * rhi);
        aqB[1] = *reinterpret_cast<const bf16x8*>(qb + qrB * DH_ + 32 + 8 * rhi);
    }

    float mA = NEG_INF, lAc = 0.f, mB = NEG_INF, lBc = 0.f;
    f32x4 oA[4] = {}, oB[4] = {};

    auto STAGE = [&](int bs, int t) {
        const __bf16* ksrc = kb + (long)(t * 64 + srow) * DH_ + sc0 * 8;
        async_copy16(ksrc,           &Ks[bs][wid * 16][0]);
        async_copy16(ksrc + 8 * DH_, &Ks[bs][wid * 16 + 8][0]);
        const __bf16* vsrc = vtb + (long)srow * T_ + t * 64 + sc0 * 8;
        async_copy16(vsrc,           &Vs[bs][wid * 16][0]);
        async_copy16(vsrc + 8 * T_,  &Vs[bs][wid * 16 + 8][0]);
    };

    // qrow = absolute q row for this lane (q = rlo within wave's 16 rows)
    auto PROCESS = [&](int bs, int t, int tq, int qrow, bf16x8* aq,
                       float& m_, float& l_, f32x4* o) {
        int kt0 = t * 64;
        // S^T = K Q^T: s[f][r] = S[key = kt0+f*16+rhi*4+r][q = qrow]
        f32x4 s[4];
        #pragma unroll
        for (int f = 0; f < 4; f++) {
            f32x4 accs = {};
            int kr = f * 16 + rlo;
            #pragma unroll
            for (int kk = 0; kk < 2; kk++) {
                bf16x8 ak = *reinterpret_cast<const bf16x8*>(
                    &Ks[bs][kr][((kk * 4 + rhi) ^ (kr & 7)) * 8]);
                accs = __builtin_amdgcn_mfma_f32_16x16x32_bf16(ak, aq[kk], accs, 0, 0, 0);
            }
            s[f] = accs;
        }

        // scale (log2 domain) + causal mask (diagonal tile only)
        bool diag = (t == tq);
        int kbase = kt0 + rhi * 4;
        #pragma unroll
        for (int f = 0; f < 4; f++) {
            #pragma unroll
            for (int r = 0; r < 4; r++) {
                float sv = s[f][r] * SCL;
                if (diag && (kbase + f * 16 + r > qrow)) sv = NEG_INF;
                s[f][r] = sv;
            }
        }

        // in-lane row max (16 values) + 2 cross-rhi shuffles
        f32x4 mx = s[0];
        mx = (mx > s[1]) ? mx : s[1];   // elementwise via manual fmax below
        #pragma unroll
        for (int r = 0; r < 4; r++) mx[r] = fmaxf(fmaxf(s[0][r], s[1][r]),
                                                  fmaxf(s[2][r], s[3][r]));
        float pm = fmaxf(fmaxf(mx[0], mx[1]), fmaxf(mx[2], mx[3]));
        pm = fmaxf(pm, __shfl_xor(pm, 16));
        pm = fmaxf(pm, __shfl_xor(pm, 32));

        // defer-max: skip rescale when tile max doesn't exceed m+8 (log2 dom)
        bool need = !__all(pm <= m_ + 8.f);
        if (need) {
            float nm = fmaxf(m_, pm);
            float so = EXP2F(m_ - nm);
            m_ = nm;
            l_ *= so;
            // redistribute so to the o-rows this lane accumulates (q'=rhi*4+r)
            float sov[4];
            #pragma unroll
            for (int r = 0; r < 4; r++) sov[r] = __shfl(so, rhi * 4 + r);
            #pragma unroll
            for (int fd = 0; fd < 4; fd++)
                #pragma unroll
                for (int r = 0; r < 4; r++)
                    o[fd][r] *= sov[r];
        }

        // p = exp2(s - m), in-lane sum + 2 shuffles
        float rsum = 0.f;
        #pragma unroll
        for (int f = 0; f < 4; f++)
            #pragma unroll
            for (int r = 0; r < 4; r++) {
                float pv = EXP2F(s[f][r] - m_);
                s[f][r] = pv;
                rsum += pv;
            }
        rsum += __shfl_xor(rsum, 16);
        rsum += __shfl_xor(rsum, 32);
        l_ += rsum;

        // P pack: 4 consecutive keys per (f) -> b64 swizzled write
        // layout: key Kx at elem q*64 + ((Kx>>3)^(q&7))*8 + (Kx&7)
        #pragma unroll
        for (int f = 0; f < 4; f++) {
            bf16x4 pw = { (__bf16)s[f][0], (__bf16)s[f][1],
                          (__bf16)s[f][2], (__bf16)s[f][3] };
            int keyb = f * 16 + rhi * 4;
            int c16 = keyb >> 3, sub = (keyb >> 2) & 1;
            *reinterpret_cast<bf16x4*>(
                &Pl[wid][rlo][((c16 ^ (rlo & 7)) << 3) + (sub << 2)]) = pw;
        }

        // O += P V  (A=P from Pl, B=V^T from Vs) — unchanged proven path
        #pragma unroll
        for (int kk = 0; kk < 2; kk++) {
            int ck = kk * 4 + rhi;
            bf16x8 ap = *reinterpret_cast<const bf16x8*>(&Pl[wid][rlo][(ck ^ (rlo & 7)) * 8]);
            #pragma unroll
            for (int fd = 0; fd < 4; fd++) {
                int vr = fd * 16 + rlo;
                bf16x8 bv = *reinterpret_cast<const bf16x8*>(
                    &Vs[bs][vr][(ck ^ (vr & 7)) * 8]);
                o[fd] = __builtin_amdgcn_mfma_f32_16x16x32_bf16(ap, bv, o[fd], 0, 0, 0);
            }
        }
    };

    int qrowA = tA * 64 + wid * 16 + rlo;
    int qrowB = tB * 64 + wid * 16 + rlo;

    int nsteps = tA + 1;
    STAGE(0, 0);
    __syncthreads();

    for (int t = 0; t < nsteps; ++t) {
        int cur = t & 1;
        if (t + 1 < nsteps) STAGE(cur ^ 1, t + 1);   // prefetch next tile
        PROCESS(cur, t, tA, qrowA, aqA, mA, lAc, oA);
        if (t <= tB) PROCESS(cur, t, tB, qrowB, aqB, mB, lBc, oB);
        __syncthreads();   // drains vmcnt (prefetch done) + WAR on buffers
    }

    // epilogue: broadcast l to o-rows, normalize, write both q-tiles
    float lvA[4], lvB[4];
    #pragma unroll
    for (int r = 0; r < 4; r++) {
        lvA[r] = __shfl(lAc, rhi * 4 + r);
        lvB[r] = __shfl(lBc, rhi * 4 + r);
    }
    #pragma unroll
    for (int r = 0; r < 4; r++) {
        float invA = 1.f / lvA[r];
        float invB = 1.f / lvB[r];
        long qrA = (long)tA * 64 + wid * 16 + rhi * 4 + r;
        long qrB = (long)tB * 64 + wid * 16 + rhi * 4 + r;
        #pragma unroll
        for (int fd = 0; fd < 4; fd++) {
            int d = fd * 16 + rlo;
            attout[((long)b * T_ + qrA) * E_ + h * DH_ + d] = (__bf16)(oA[fd][r] * invA);
            attout[((long)b * T_ + qrB) * E_ + h * DH_ + d] = (__bf16)(oB[fd][r] * invB);
        }
    }
}

// ---------------------------------------------------------------- launcher
extern "C" void kernel_launch(void* const* d_in, const int* in_sizes, int n_in,
                              void* d_out, int out_size, void* d_ws, size_t ws_size,
                              hipStream_t stream) {
    const float* x  = (const float*)d_in[0];
    const float* Wq = (const float*)d_in[1];
    const float* Wk = (const float*)d_in[2];
    const float* Wv = (const float*)d_in[3];
    const float* Wp = (const float*)d_in[4];
    const float* bp = (const float*)d_in[5];

    char* ws = (char*)d_ws;
    const long SZ_XE = (long)B_ * T_ * E_ * 2;      // 16 MB (bf16 [B*T][E])
    const long SZ_W  = (long)H_ * DH_ * E_ * 2;     // 2 MB
    __bf16* xb  = (__bf16*)(ws);                    // x bf16; REUSED as attout after QKV
    __bf16* qb  = (__bf16*)(ws + SZ_XE);
    __bf16* kb  = (__bf16*)(ws + 2 * SZ_XE);
    __bf16* vt  = (__bf16*)(ws + 3 * SZ_XE);        // V^T: [B*H][DH][T]
    __bf16* wqt = (__bf16*)(ws + 4 * SZ_XE);
    __bf16* wkt = (__bf16*)(ws + 4 * SZ_XE + SZ_W);
    __bf16* wvt = (__bf16*)(ws + 4 * SZ_XE + 2 * SZ_W);
    __bf16* wpb = (__bf16*)(ws + 4 * SZ_XE + 3 * SZ_W);
    __bf16* att = xb;  // alias: xb dead after QKV GEMMs (stream-ordered)

    // casts
    cast_f32_to_bf16<<<8192, 256, 0, stream>>>(x, xb, B_ * T_ * E_);
    cast_transpose_w<<<4096, 256, 0, stream>>>(Wq, wqt);
    cast_transpose_w<<<4096, 256, 0, stream>>>(Wk, wkt);
    cast_transpose_w<<<4096, 256, 0, stream>>>(Wv, wvt);
    cast_f32_to_bf16<<<1024, 256, 0, stream>>>(Wp, wpb, E_ * E_);

    // QKV projections: per z=(b*H+h): C[T][DH] = X_b[T][E] @ W_h[DH][E]^T
    long sA = (long)T_ * E_, sB = (long)DH_ * E_, sC = (long)T_ * DH_;
    gemm_bt<0><<<dim3(T_ / BM, 1, B_ * H_), 256, 0, stream>>>(
        xb, wqt, qb, nullptr, E_, DH_, sA, sB, sC, H_, 0);
    gemm_bt<0><<<dim3(T_ / BM, 1, B_ * H_), 256, 0, stream>>>(
        xb, wkt, kb, nullptr, E_, DH_, sA, sB, sC, H_, 0);
    // V projection writes V^T directly: vt[bh][d][t]
    gemm_bt<2><<<dim3(T_ / BM, 1, B_ * H_), 256, 0, stream>>>(
        xb, wvt, vt, nullptr, E_, DH_, sA, sB, sC, H_, T_);

    // causal attention (fused paired q-tiles, swapped-QK^T softmax)
    attn_kernel<<<dim3(16, B_ * H_), 256, 0, stream>>>(qb, kb, vt, att);

    // output projection + bias (fp32 out)
    gemm_bt<1><<<dim3((B_ * T_) / BM, E_ / BN, 1), 256, 0, stream>>>(
        att, wpb, (float*)d_out, bp, E_, E_, 0, 0, 0, 1, 0);
}

// Round 6
// 173.089 us; speedup vs baseline: 2.8888x; 1.3483x over previous
//
#include <hip/hip_runtime.h>
#include <hip/hip_bf16.h>

// Problem constants
#define B_ 4
#define T_ 2048
#define E_ 1024
#define H_ 16
#define DH_ 64

typedef __bf16 bf16x8 __attribute__((ext_vector_type(8)));
typedef __bf16 bf16x4 __attribute__((ext_vector_type(4)));
typedef float f32x4 __attribute__((ext_vector_type(4)));

#define EXP2F(x) __builtin_amdgcn_exp2f(x)
#define NEG_INF (-__builtin_inff())

// async global->LDS, 16B per lane: lane l writes lds_base + l*16
__device__ __forceinline__ void async_copy16(const __bf16* g, __bf16* l) {
    __builtin_amdgcn_global_load_lds(
        (const __attribute__((address_space(1))) unsigned int*)g,
        (__attribute__((address_space(3))) unsigned int*)l, 16, 0, 0);
}

// ---------------------------------------------------------------- casts
__global__ void cast_f32_to_bf16(const float* __restrict__ src,
                                 __bf16* __restrict__ dst, int n) {
    int i = (blockIdx.x * blockDim.x + threadIdx.x) * 4;
    if (i + 3 < n) {
        float4 f = *reinterpret_cast<const float4*>(src + i);
        bf16x4 o = { (__bf16)f.x, (__bf16)f.y, (__bf16)f.z, (__bf16)f.w };
        *reinterpret_cast<bf16x4*>(dst + i) = o;
    }
}

// build wcat[3072][1024]: rows 0-1023 = Wq (n = h*64+d), 1024-2047 = Wk, 2048-3071 = Wv
// src layout [H][E][DH]
__global__ void cast_wcat(const float* __restrict__ Wq, const float* __restrict__ Wk,
                          const float* __restrict__ Wv, __bf16* __restrict__ out) {
    int idx = blockIdx.x * blockDim.x + threadIdx.x;   // over 3072*1024
    int e = idx & (E_ - 1);
    int n = idx >> 10;
    int rem = n & 1023, h = rem >> 6, d = rem & 63;
    const float* src = (n < 1024) ? Wq : (n < 2048 ? Wk : Wv);
    out[idx] = (__bf16)src[((h << 10) + e) * DH_ + d];
}

// ---------------------------------------------------------------- GEMM v2 (C = A * Bt^T)
// 128x128 tile, BK=64, 4 waves (2x2), global_load_lds staging (pre-swizzled src).
// MODE 1: C[m][N] f32 + bias.   MODE 3: QKV epilogue -> q/k [bh][t][d], vt [bh][d][t].
template<int MODE>
__global__ __launch_bounds__(256, 3) void gemm128(
    const __bf16* __restrict__ A, const __bf16* __restrict__ Bt,
    float* __restrict__ Cf, const float* __restrict__ bias,
    __bf16* __restrict__ oq, __bf16* __restrict__ ok, __bf16* __restrict__ ovt,
    int K, int N) {

    __shared__ __bf16 As[128][64];
    __shared__ __bf16 Bs[128][64];

    int tid = threadIdx.x, lane = tid & 63, wid = tid >> 6;
    int wr = wid >> 1, wc = wid & 1;
    int rlo = lane & 15, rhi = lane >> 4;
    int l8 = lane >> 3, c = lane & 7;

    const __bf16* Ab = A + (long)blockIdx.x * 128 * K;
    const __bf16* Bb = Bt + (long)blockIdx.y * 128 * K;

    f32x4 acc[4][4] = {};

    for (int k0 = 0; k0 < K; k0 += 64) {
        // stage A tile (128x64) + B tile (128x64): linear LDS dest,
        // pre-swizzled global source chunk (involution c ^ (row&7))
        #pragma unroll
        for (int p = 0; p < 4; p++) {
            int gr = p * 32 + wid * 8 + l8;
            int sc = c ^ (gr & 7);
            async_copy16(Ab + (long)gr * K + k0 + sc * 8, &As[p * 32 + wid * 8][0]);
        }
        #pragma unroll
        for (int p = 0; p < 4; p++) {
            int gr = p * 32 + wid * 8 + l8;
            int sc = c ^ (gr & 7);
            async_copy16(Bb + (long)gr * K + k0 + sc * 8, &Bs[p * 32 + wid * 8][0]);
        }
        __syncthreads();   // drains vmcnt -> tiles ready

        #pragma unroll
        for (int kk = 0; kk < 2; kk++) {
            bf16x8 af[4], bfr[4];
            #pragma unroll
            for (int mi = 0; mi < 4; mi++) {
                int r = wr * 64 + mi * 16 + rlo;
                af[mi] = *reinterpret_cast<const bf16x8*>(
                    &As[r][((kk * 4 + rhi) ^ (r & 7)) * 8]);
            }
            #pragma unroll
            for (int ni = 0; ni < 4; ni++) {
                int r = wc * 64 + ni * 16 + rlo;
                bfr[ni] = *reinterpret_cast<const bf16x8*>(
                    &Bs[r][((kk * 4 + rhi) ^ (r & 7)) * 8]);
            }
            #pragma unroll
            for (int mi = 0; mi < 4; mi++)
                #pragma unroll
                for (int ni = 0; ni < 4; ni++)
                    acc[mi][ni] = __builtin_amdgcn_mfma_f32_16x16x32_bf16(
                        af[mi], bfr[ni], acc[mi][ni], 0, 0, 0);
        }
        __syncthreads();   // WAR before next stage
    }

    // epilogue: C row = 4*rhi + reg, col = rlo (verified gfx950 C/D layout)
    long m0 = (long)blockIdx.x * 128 + wr * 64;
    int n0 = blockIdx.y * 128 + wc * 64;

    if constexpr (MODE == 1) {
        #pragma unroll
        for (int mi = 0; mi < 4; mi++) {
            #pragma unroll
            for (int ni = 0; ni < 4; ni++) {
                int cn = n0 + ni * 16 + rlo;
                #pragma unroll
                for (int r = 0; r < 4; r++) {
                    long rm = m0 + mi * 16 + rhi * 4 + r;
                    Cf[rm * N + cn] = acc[mi][ni][r] + bias[cn];
                }
            }
        }
    } else {
        int type = blockIdx.y >> 3;   // 0=q, 1=k, 2=v (N=3072, 8 n-blocks each)
        #pragma unroll
        for (int mi = 0; mi < 4; mi++) {
            long m_ = m0 + mi * 16 + rhi * 4;
            int b = (int)(m_ >> 11);
            int t0 = (int)(m_ & 2047);
            #pragma unroll
            for (int ni = 0; ni < 4; ni++) {
                int n = n0 + ni * 16 + rlo;
                int rem = n & 1023, h = rem >> 6, d = rem & 63;
                long bh = b * 16 + h;
                if (type == 2) {
                    // vt[bh][d][t]: 4 consecutive t -> bf16x4
                    bf16x4 o = { (__bf16)acc[mi][ni][0], (__bf16)acc[mi][ni][1],
                                 (__bf16)acc[mi][ni][2], (__bf16)acc[mi][ni][3] };
                    *reinterpret_cast<bf16x4*>(ovt + (bh * 64 + d) * 2048 + t0) = o;
                } else {
                    __bf16* dst = (type ? ok : oq) + bh * 2048 * 64;
                    #pragma unroll
                    for (int r = 0; r < 4; r++)
                        dst[(long)(t0 + r) * 64 + d] = (__bf16)acc[mi][ni][r];
                }
            }
        }
    }
}

// ---------------------------------------------------------------- attention
// grid (16, 64); 256 threads = 4 waves. fid remapped so each (b,h)'s 16
// blocks land on ONE XCD. Block handles q-tiles {31-p, p} fused over one KV
// sweep; PROCESS merged: K-frags read once, feed both q-tiles' QK^T.
__global__ __launch_bounds__(256, 4) void attn_kernel(
    const __bf16* __restrict__ q, const __bf16* __restrict__ k,
    const __bf16* __restrict__ vt, __bf16* __restrict__ attout) {

    __shared__ __bf16 Ks[2][64][64];
    __shared__ __bf16 Vs[2][64][64];
    __shared__ __bf16 Pl[4][16][64];

    int tid = threadIdx.x, lane = tid & 63, wid = tid >> 6;
    int rlo = lane & 15, rhi = lane >> 4;

    int fid = blockIdx.y * 16 + blockIdx.x;
    int xcd = fid & 7, slot = fid >> 3;     // round-robin XCD assumption (perf-only)
    int bh = xcd * 8 + (slot >> 4);         // 8 bh per XCD
    int p = slot & 15;
    int tA = 31 - p, tB = p;                // q-tile indices (64-row tiles)

    int b = bh >> 4, h = bh & 15;
    const __bf16* qb = q + (long)bh * T_ * DH_;
    const __bf16* kb = k + (long)bh * T_ * DH_;
    const __bf16* vtb = vt + (long)bh * T_ * DH_;   // [DH][T]

    const float SCL = 0.125f * 1.44269504088896340736f;  // 1/8 * log2(e)

    // staging geometry (pre-swizzled global source, linear LDS dest)
    int srow = wid * 16 + (lane >> 3);
    int sc0 = (lane & 7) ^ (srow & 7);

    // Q fragments for both tiles (rlo = q row; rhi = d-chunk)
    bf16x8 aqA[2], aqB[2];
    {
        long qrA = (long)tA * 64 + wid * 16 + rlo;
        aqA[0] = *reinterpret_cast<const bf16x8*>(qb + qrA * DH_ + 8 * rhi);
        aqA[1] = *reinterpret_cast<const bf16x8*>(qb + qrA * DH_ + 32 + 8 * rhi);
        long qrB = (long)tB * 64 + wid * 16 + rlo;
        aqB[0] = *reinterpret_cast<const bf16x8*>(qb + qrB * DH_ + 8 * rhi);
        aqB[1] = *reinterpret_cast<const bf16x8*>(qb + qrB * DH_ + 32 + 8 * rhi);
    }

    float mA = NEG_INF, lAc = 0.f, mB = NEG_INF, lBc = 0.f;
    f32x4 oA[4] = {}, oB[4] = {};

    auto STAGE = [&](int bs, int t) {
        const __bf16* ksrc = kb + (long)(t * 64 + srow) * DH_ + sc0 * 8;
        async_copy16(ksrc,           &Ks[bs][wid * 16][0]);
        async_copy16(ksrc + 8 * DH_, &Ks[bs][wid * 16 + 8][0]);
        const __bf16* vsrc = vtb + (long)srow * T_ + t * 64 + sc0 * 8;
        async_copy16(vsrc,           &Vs[bs][wid * 16][0]);
        async_copy16(vsrc + 8 * T_,  &Vs[bs][wid * 16 + 8][0]);
    };

    // causal mask on RAW scores (masked -> -inf)
    auto APPLYMASK = [&](f32x4* s, int qrow, int kt0) {
        int kbase = kt0 + rhi * 4;
        #pragma unroll
        for (int f = 0; f < 4; f++)
            #pragma unroll
            for (int r = 0; r < 4; r++)
                if (kbase + f * 16 + r > qrow) s[f][r] = NEG_INF;
    };

    // online softmax on raw s (max on raw, exp2(fma(s,SCL,-m))), then PV
    auto SOFTMAX_PV = [&](int bs, f32x4* s, float& m_, float& l_, f32x4* o) {
        // in-lane max of 16 raw values + 2 cross-rhi shuffles (covers all 4 rhi)
        float pm;
        {
            f32x4 mx;
            #pragma unroll
            for (int r = 0; r < 4; r++)
                mx[r] = fmaxf(fmaxf(s[0][r], s[1][r]), fmaxf(s[2][r], s[3][r]));
            pm = fmaxf(fmaxf(mx[0], mx[1]), fmaxf(mx[2], mx[3]));
            pm = fmaxf(pm, __shfl_xor(pm, 16));
            pm = fmaxf(pm, __shfl_xor(pm, 32));
        }
        float pms = pm * SCL;   // scaled-domain tile max

        // defer-max: skip rescale while tile max stays within m+8 (log2 dom)
        bool need = !__all(pms <= m_ + 8.f);
        if (need) {
            float nm = fmaxf(m_, pms);
            float so = EXP2F(m_ - nm);
            m_ = nm;
            l_ *= so;
            float sov[4];
            #pragma unroll
            for (int r = 0; r < 4; r++) sov[r] = __shfl(so, rhi * 4 + r);
            #pragma unroll
            for (int fd = 0; fd < 4; fd++)
                #pragma unroll
                for (int r = 0; r < 4; r++)
                    o[fd][r] *= sov[r];
        }

        // p = exp2(s*SCL - m) via fma; in-lane sum + 2 shuffles
        float rsum = 0.f;
        #pragma unroll
        for (int f = 0; f < 4; f++)
            #pragma unroll
            for (int r = 0; r < 4; r++) {
                float pv = EXP2F(fmaf(s[f][r], SCL, -m_));
                s[f][r] = pv;
                rsum += pv;
            }
        rsum += __shfl_xor(rsum, 16);
        rsum += __shfl_xor(rsum, 32);
        l_ += rsum;

        // P pack: 4 consecutive keys -> b64 swizzled write
        #pragma unroll
        for (int f = 0; f < 4; f++) {
            bf16x4 pw = { (__bf16)s[f][0], (__bf16)s[f][1],
                          (__bf16)s[f][2], (__bf16)s[f][3] };
            int keyb = f * 16 + rhi * 4;
            int c16 = keyb >> 3, sub = (keyb >> 2) & 1;
            *reinterpret_cast<bf16x4*>(
                &Pl[wid][rlo][((c16 ^ (rlo & 7)) << 3) + (sub << 2)]) = pw;
        }

        // O += P V  (A=P from Pl, B=V^T from Vs)
        #pragma unroll
        for (int kk = 0; kk < 2; kk++) {
            int ck = kk * 4 + rhi;
            bf16x8 ap = *reinterpret_cast<const bf16x8*>(&Pl[wid][rlo][(ck ^ (rlo & 7)) * 8]);
            #pragma unroll
            for (int fd = 0; fd < 4; fd++) {
                int vr = fd * 16 + rlo;
                bf16x8 bv = *reinterpret_cast<const bf16x8*>(
                    &Vs[bs][vr][(ck ^ (vr & 7)) * 8]);
                o[fd] = __builtin_amdgcn_mfma_f32_16x16x32_bf16(ap, bv, o[fd], 0, 0, 0);
            }
        }
    };

    int qrowA = tA * 64 + wid * 16 + rlo;
    int qrowB = tB * 64 + wid * 16 + rlo;

    int nsteps = tA + 1;
    STAGE(0, 0);
    __syncthreads();

    for (int t = 0; t < nsteps; ++t) {
        int cur = t & 1;
        if (t + 1 < nsteps) STAGE(cur ^ 1, t + 1);   // prefetch next tile

        bool doB = (t <= tB);
        // QK^T for both q-tiles, K-fragments read ONCE
        f32x4 sA[4], sB[4];
        #pragma unroll
        for (int f = 0; f < 4; f++) {
            int kr = f * 16 + rlo;
            bf16x8 ak0 = *reinterpret_cast<const bf16x8*>(
                &Ks[cur][kr][((0 + rhi) ^ (kr & 7)) * 8]);
            bf16x8 ak1 = *reinterpret_cast<const bf16x8*>(
                &Ks[cur][kr][((4 + rhi) ^ (kr & 7)) * 8]);
            f32x4 a0 = {};
            a0 = __builtin_amdgcn_mfma_f32_16x16x32_bf16(ak0, aqA[0], a0, 0, 0, 0);
            a0 = __builtin_amdgcn_mfma_f32_16x16x32_bf16(ak1, aqA[1], a0, 0, 0, 0);
            sA[f] = a0;
            if (doB) {
                f32x4 b0 = {};
                b0 = __builtin_amdgcn_mfma_f32_16x16x32_bf16(ak0, aqB[0], b0, 0, 0, 0);
                b0 = __builtin_amdgcn_mfma_f32_16x16x32_bf16(ak1, aqB[1], b0, 0, 0, 0);
                sB[f] = b0;
            }
        }

        if (t == tA) APPLYMASK(sA, qrowA, t * 64);
        SOFTMAX_PV(cur, sA, mA, lAc, oA);
        if (doB) {
            if (t == tB) APPLYMASK(sB, qrowB, t * 64);
            SOFTMAX_PV(cur, sB, mB, lBc, oB);
        }
        __syncthreads();   // drains prefetch vmcnt + WAR on buffers
    }

    // epilogue: broadcast l to o-rows, normalize, write both q-tiles
    float lvA[4], lvB[4];
    #pragma unroll
    for (int r = 0; r < 4; r++) {
        lvA[r] = __shfl(lAc, rhi * 4 + r);
        lvB[r] = __shfl(lBc, rhi * 4 + r);
    }
    #pragma unroll
    for (int r = 0; r < 4; r++) {
        float invA = 1.f / lvA[r];
        float invB = 1.f / lvB[r];
        long qrA = (long)tA * 64 + wid * 16 + rhi * 4 + r;
        long qrB = (long)tB * 64 + wid * 16 + rhi * 4 + r;
        #pragma unroll
        for (int fd = 0; fd < 4; fd++) {
            int d = fd * 16 + rlo;
            attout[((long)b * T_ + qrA) * E_ + h * DH_ + d] = (__bf16)(oA[fd][r] * invA);
            attout[((long)b * T_ + qrB) * E_ + h * DH_ + d] = (__bf16)(oB[fd][r] * invB);
        }
    }
}

// ---------------------------------------------------------------- launcher
extern "C" void kernel_launch(void* const* d_in, const int* in_sizes, int n_in,
                              void* d_out, int out_size, void* d_ws, size_t ws_size,
                              hipStream_t stream) {
    const float* x  = (const float*)d_in[0];
    const float* Wq = (const float*)d_in[1];
    const float* Wk = (const float*)d_in[2];
    const float* Wv = (const float*)d_in[3];
    const float* Wp = (const float*)d_in[4];
    const float* bp = (const float*)d_in[5];

    char* ws = (char*)d_ws;
    const long SZ_XE = (long)B_ * T_ * E_ * 2;      // 16 MB (bf16 [B*T][E])
    __bf16* xb   = (__bf16*)(ws);                   // x bf16; REUSED as attout after QKV
    __bf16* qb   = (__bf16*)(ws + SZ_XE);
    __bf16* kb   = (__bf16*)(ws + 2 * SZ_XE);
    __bf16* vt   = (__bf16*)(ws + 3 * SZ_XE);       // V^T: [B*H][DH][T]
    __bf16* wcat = (__bf16*)(ws + 4 * SZ_XE);       // [3072][1024] bf16 (6 MB)
    __bf16* wpb  = (__bf16*)(ws + 4 * SZ_XE + (long)3072 * 1024 * 2);
    __bf16* att  = xb;  // alias: xb dead after QKV GEMM (stream-ordered)

    // casts
    cast_f32_to_bf16<<<8192, 256, 0, stream>>>(x, xb, B_ * T_ * E_);
    cast_wcat<<<12288, 256, 0, stream>>>(Wq, Wk, Wv, wcat);
    cast_f32_to_bf16<<<1024, 256, 0, stream>>>(Wp, wpb, E_ * E_);

    // fused QKV projection: [8192][1024] @ wcat^T -> q/k [bh][t][d], vt [bh][d][t]
    gemm128<3><<<dim3(64, 24), 256, 0, stream>>>(
        xb, wcat, nullptr, nullptr, qb, kb, vt, E_, 3 * E_);

    // causal attention (fused paired q-tiles, merged PROCESS)
    attn_kernel<<<dim3(16, B_ * H_), 256, 0, stream>>>(qb, kb, vt, att);

    // output projection + bias (fp32 out)
    gemm128<1><<<dim3(64, 8), 256, 0, stream>>>(
        att, wpb, (float*)d_out, bp, nullptr, nullptr, nullptr, E_, E_);
}

// Round 7
// 164.742 us; speedup vs baseline: 3.0352x; 1.0507x over previous
//
#include <hip/hip_runtime.h>
#include <hip/hip_bf16.h>

// Problem constants
#define B_ 4
#define T_ 2048
#define E_ 1024
#define H_ 16
#define DH_ 64

typedef __bf16 bf16x8 __attribute__((ext_vector_type(8)));
typedef __bf16 bf16x4 __attribute__((ext_vector_type(4)));
typedef float f32x4 __attribute__((ext_vector_type(4)));

#define EXP2F(x) __builtin_amdgcn_exp2f(x)
#define NEG_INF (-__builtin_inff())

// async global->LDS, 16B per lane: lane l writes lds_base + l*16
__device__ __forceinline__ void async_copy16(const __bf16* g, __bf16* l) {
    __builtin_amdgcn_global_load_lds(
        (const __attribute__((address_space(1))) unsigned int*)g,
        (__attribute__((address_space(3))) unsigned int*)l, 16, 0, 0);
}

// ---------------------------------------------------------------- casts
__global__ void cast_f32_to_bf16(const float* __restrict__ src,
                                 __bf16* __restrict__ dst, int n) {
    int i = (blockIdx.x * blockDim.x + threadIdx.x) * 4;
    if (i + 3 < n) {
        float4 f = *reinterpret_cast<const float4*>(src + i);
        bf16x4 o = { (__bf16)f.x, (__bf16)f.y, (__bf16)f.z, (__bf16)f.w };
        *reinterpret_cast<bf16x4*>(dst + i) = o;
    }
}

// build wcat[3072][1024]: rows 0-1023 = Wq (n = h*64+d), 1024-2047 = Wk, 2048-3071 = Wv
// src layout [H][E][DH]
__global__ void cast_wcat(const float* __restrict__ Wq, const float* __restrict__ Wk,
                          const float* __restrict__ Wv, __bf16* __restrict__ out) {
    int idx = blockIdx.x * blockDim.x + threadIdx.x;   // over 3072*1024
    int e = idx & (E_ - 1);
    int n = idx >> 10;
    int rem = n & 1023, h = rem >> 6, d = rem & 63;
    const float* src = (n < 1024) ? Wq : (n < 2048 ? Wk : Wv);
    out[idx] = (__bf16)src[((h << 10) + e) * DH_ + d];
}

// ---------------------------------------------------------------- GEMM v2 (C = A * Bt^T)
// 128x128 tile, BK=64, 4 waves (2x2), global_load_lds staging (pre-swizzled src).
// MODE 1: C[m][N] f32 + bias.   MODE 3: QKV epilogue -> q/k [bh][t][d], vt [bh][d][t].
template<int MODE>
__global__ __launch_bounds__(256, 3) void gemm128(
    const __bf16* __restrict__ A, const __bf16* __restrict__ Bt,
    float* __restrict__ Cf, const float* __restrict__ bias,
    __bf16* __restrict__ oq, __bf16* __restrict__ ok, __bf16* __restrict__ ovt,
    int K, int N) {

    __shared__ __bf16 As[128][64];
    __shared__ __bf16 Bs[128][64];

    int tid = threadIdx.x, lane = tid & 63, wid = tid >> 6;
    int wr = wid >> 1, wc = wid & 1;
    int rlo = lane & 15, rhi = lane >> 4;
    int l8 = lane >> 3, c = lane & 7;

    const __bf16* Ab = A + (long)blockIdx.x * 128 * K;
    const __bf16* Bb = Bt + (long)blockIdx.y * 128 * K;

    f32x4 acc[4][4] = {};

    for (int k0 = 0; k0 < K; k0 += 64) {
        #pragma unroll
        for (int p = 0; p < 4; p++) {
            int gr = p * 32 + wid * 8 + l8;
            int sc = c ^ (gr & 7);
            async_copy16(Ab + (long)gr * K + k0 + sc * 8, &As[p * 32 + wid * 8][0]);
        }
        #pragma unroll
        for (int p = 0; p < 4; p++) {
            int gr = p * 32 + wid * 8 + l8;
            int sc = c ^ (gr & 7);
            async_copy16(Bb + (long)gr * K + k0 + sc * 8, &Bs[p * 32 + wid * 8][0]);
        }
        __syncthreads();   // drains vmcnt -> tiles ready

        #pragma unroll
        for (int kk = 0; kk < 2; kk++) {
            bf16x8 af[4], bfr[4];
            #pragma unroll
            for (int mi = 0; mi < 4; mi++) {
                int r = wr * 64 + mi * 16 + rlo;
                af[mi] = *reinterpret_cast<const bf16x8*>(
                    &As[r][((kk * 4 + rhi) ^ (r & 7)) * 8]);
            }
            #pragma unroll
            for (int ni = 0; ni < 4; ni++) {
                int r = wc * 64 + ni * 16 + rlo;
                bfr[ni] = *reinterpret_cast<const bf16x8*>(
                    &Bs[r][((kk * 4 + rhi) ^ (r & 7)) * 8]);
            }
            #pragma unroll
            for (int mi = 0; mi < 4; mi++)
                #pragma unroll
                for (int ni = 0; ni < 4; ni++)
                    acc[mi][ni] = __builtin_amdgcn_mfma_f32_16x16x32_bf16(
                        af[mi], bfr[ni], acc[mi][ni], 0, 0, 0);
        }
        __syncthreads();   // WAR before next stage
    }

    long m0 = (long)blockIdx.x * 128 + wr * 64;
    int n0 = blockIdx.y * 128 + wc * 64;

    if constexpr (MODE == 1) {
        #pragma unroll
        for (int mi = 0; mi < 4; mi++) {
            #pragma unroll
            for (int ni = 0; ni < 4; ni++) {
                int cn = n0 + ni * 16 + rlo;
                #pragma unroll
                for (int r = 0; r < 4; r++) {
                    long rm = m0 + mi * 16 + rhi * 4 + r;
                    Cf[rm * N + cn] = acc[mi][ni][r] + bias[cn];
                }
            }
        }
    } else {
        int type = blockIdx.y >> 3;   // 0=q, 1=k, 2=v (N=3072, 8 n-blocks each)
        #pragma unroll
        for (int mi = 0; mi < 4; mi++) {
            long m_ = m0 + mi * 16 + rhi * 4;
            int b = (int)(m_ >> 11);
            int t0 = (int)(m_ & 2047);
            #pragma unroll
            for (int ni = 0; ni < 4; ni++) {
                int n = n0 + ni * 16 + rlo;
                int rem = n & 1023, h = rem >> 6, d = rem & 63;
                long bh = b * 16 + h;
                if (type == 2) {
                    bf16x4 o = { (__bf16)acc[mi][ni][0], (__bf16)acc[mi][ni][1],
                                 (__bf16)acc[mi][ni][2], (__bf16)acc[mi][ni][3] };
                    *reinterpret_cast<bf16x4*>(ovt + (bh * 64 + d) * 2048 + t0) = o;
                } else {
                    __bf16* dst = (type ? ok : oq) + bh * 2048 * 64;
                    #pragma unroll
                    for (int r = 0; r < 4; r++)
                        dst[(long)(t0 + r) * 64 + d] = (__bf16)acc[mi][ni][r];
                }
            }
        }
    }
}

// ---------------------------------------------------------------- attention
// grid (16, 64); 256 threads = 4 waves. fid remapped so each (b,h)'s 16
// blocks land on ONE XCD. Block handles q-tiles {31-p, p} fused over one KV
// sweep; merged PROCESS (shared K-frags). 2-deep prefetch pipeline with
// COUNTED vmcnt (never drain to 0 in steady state) + raw s_barrier.
__global__ __launch_bounds__(256, 4) void attn_kernel(
    const __bf16* __restrict__ q, const __bf16* __restrict__ k,
    const __bf16* __restrict__ vt, __bf16* __restrict__ attout) {

    __shared__ __bf16 Ks[2][64][64];
    __shared__ __bf16 Vs[2][64][64];
    __shared__ __bf16 Pl[4][16][64];

    int tid = threadIdx.x, lane = tid & 63, wid = tid >> 6;
    int rlo = lane & 15, rhi = lane >> 4;

    int fid = blockIdx.y * 16 + blockIdx.x;
    int xcd = fid & 7, slot = fid >> 3;     // round-robin XCD assumption (perf-only)
    int bh = xcd * 8 + (slot >> 4);         // 8 bh per XCD
    int p = slot & 15;
    int tA = 31 - p, tB = p;                // q-tile indices (64-row tiles)

    int b = bh >> 4, h = bh & 15;
    const __bf16* qb = q + (long)bh * T_ * DH_;
    const __bf16* kb = k + (long)bh * T_ * DH_;
    const __bf16* vtb = vt + (long)bh * T_ * DH_;   // [DH][T]

    const float SCL = 0.125f * 1.44269504088896340736f;  // 1/8 * log2(e)

    // staging geometry (pre-swizzled global source, linear LDS dest)
    int srow = wid * 16 + (lane >> 3);
    int sc0 = (lane & 7) ^ (srow & 7);

    // Q fragments for both tiles (rlo = q row; rhi = d-chunk)
    bf16x8 aqA[2], aqB[2];
    {
        long qrA = (long)tA * 64 + wid * 16 + rlo;
        aqA[0] = *reinterpret_cast<const bf16x8*>(qb + qrA * DH_ + 8 * rhi);
        aqA[1] = *reinterpret_cast<const bf16x8*>(qb + qrA * DH_ + 32 + 8 * rhi);
        long qrB = (long)tB * 64 + wid * 16 + rlo;
        aqB[0] = *reinterpret_cast<const bf16x8*>(qb + qrB * DH_ + 8 * rhi);
        aqB[1] = *reinterpret_cast<const bf16x8*>(qb + qrB * DH_ + 32 + 8 * rhi);
    }

    float mA = NEG_INF, lAc = 0.f, mB = NEG_INF, lBc = 0.f;
    f32x4 oA[4] = {}, oB[4] = {};

    auto STAGE = [&](int bs, int t) {
        const __bf16* ksrc = kb + (long)(t * 64 + srow) * DH_ + sc0 * 8;
        async_copy16(ksrc,           &Ks[bs][wid * 16][0]);
        async_copy16(ksrc + 8 * DH_, &Ks[bs][wid * 16 + 8][0]);
        const __bf16* vsrc = vtb + (long)srow * T_ + t * 64 + sc0 * 8;
        async_copy16(vsrc,           &Vs[bs][wid * 16][0]);
        async_copy16(vsrc + 8 * T_,  &Vs[bs][wid * 16 + 8][0]);
    };

    auto APPLYMASK = [&](f32x4* s, int qrow, int kt0) {
        int kbase = kt0 + rhi * 4;
        #pragma unroll
        for (int f = 0; f < 4; f++)
            #pragma unroll
            for (int r = 0; r < 4; r++)
                if (kbase + f * 16 + r > qrow) s[f][r] = NEG_INF;
    };

    // online softmax on raw s (max on raw, exp2(fma(s,SCL,-m))), then PV
    auto SOFTMAX_PV = [&](int bs, f32x4* s, float& m_, float& l_, f32x4* o) {
        float pm;
        {
            f32x4 mx;
            #pragma unroll
            for (int r = 0; r < 4; r++)
                mx[r] = fmaxf(fmaxf(s[0][r], s[1][r]), fmaxf(s[2][r], s[3][r]));
            pm = fmaxf(fmaxf(mx[0], mx[1]), fmaxf(mx[2], mx[3]));
            pm = fmaxf(pm, __shfl_xor(pm, 16));
            pm = fmaxf(pm, __shfl_xor(pm, 32));
        }
        float pms = pm * SCL;   // scaled-domain tile max

        bool need = !__all(pms <= m_ + 8.f);
        if (need) {
            float nm = fmaxf(m_, pms);
            float so = EXP2F(m_ - nm);
            m_ = nm;
            l_ *= so;
            float sov[4];
            #pragma unroll
            for (int r = 0; r < 4; r++) sov[r] = __shfl(so, rhi * 4 + r);
            #pragma unroll
            for (int fd = 0; fd < 4; fd++)
                #pragma unroll
                for (int r = 0; r < 4; r++)
                    o[fd][r] *= sov[r];
        }

        float rsum = 0.f;
        #pragma unroll
        for (int f = 0; f < 4; f++)
            #pragma unroll
            for (int r = 0; r < 4; r++) {
                float pv = EXP2F(fmaf(s[f][r], SCL, -m_));
                s[f][r] = pv;
                rsum += pv;
            }
        rsum += __shfl_xor(rsum, 16);
        rsum += __shfl_xor(rsum, 32);
        l_ += rsum;

        // P pack: 4 consecutive keys -> b64 swizzled write
        #pragma unroll
        for (int f = 0; f < 4; f++) {
            bf16x4 pw = { (__bf16)s[f][0], (__bf16)s[f][1],
                          (__bf16)s[f][2], (__bf16)s[f][3] };
            int keyb = f * 16 + rhi * 4;
            int c16 = keyb >> 3, sub = (keyb >> 2) & 1;
            *reinterpret_cast<bf16x4*>(
                &Pl[wid][rlo][((c16 ^ (rlo & 7)) << 3) + (sub << 2)]) = pw;
        }

        // O += P V
        __builtin_amdgcn_s_setprio(1);
        #pragma unroll
        for (int kk = 0; kk < 2; kk++) {
            int ck = kk * 4 + rhi;
            bf16x8 ap = *reinterpret_cast<const bf16x8*>(&Pl[wid][rlo][(ck ^ (rlo & 7)) * 8]);
            #pragma unroll
            for (int fd = 0; fd < 4; fd++) {
                int vr = fd * 16 + rlo;
                bf16x8 bv = *reinterpret_cast<const bf16x8*>(
                    &Vs[bs][vr][(ck ^ (vr & 7)) * 8]);
                o[fd] = __builtin_amdgcn_mfma_f32_16x16x32_bf16(ap, bv, o[fd], 0, 0, 0);
            }
        }
        __builtin_amdgcn_s_setprio(0);
    };

    int qrowA = tA * 64 + wid * 16 + rlo;
    int qrowB = tB * 64 + wid * 16 + rlo;

    int nsteps = tA + 1;   // >= 17

    // prologue: 2-deep prefetch; wait for tile 0 only (vmcnt covers Q loads too)
    STAGE(0, 0);
    STAGE(1, 1);
    asm volatile("s_waitcnt vmcnt(4)" ::: "memory");
    asm volatile("s_barrier" ::: "memory");

    for (int t = 0; t < nsteps; ++t) {
        int cur = t & 1;
        bool doB = (t <= tB);

        // QK^T for both q-tiles, K-fragments read ONCE
        f32x4 sA[4], sB[4];
        __builtin_amdgcn_s_setprio(1);
        #pragma unroll
        for (int f = 0; f < 4; f++) {
            int kr = f * 16 + rlo;
            bf16x8 ak0 = *reinterpret_cast<const bf16x8*>(
                &Ks[cur][kr][((0 + rhi) ^ (kr & 7)) * 8]);
            bf16x8 ak1 = *reinterpret_cast<const bf16x8*>(
                &Ks[cur][kr][((4 + rhi) ^ (kr & 7)) * 8]);
            f32x4 a0 = {};
            a0 = __builtin_amdgcn_mfma_f32_16x16x32_bf16(ak0, aqA[0], a0, 0, 0, 0);
            a0 = __builtin_amdgcn_mfma_f32_16x16x32_bf16(ak1, aqA[1], a0, 0, 0, 0);
            sA[f] = a0;
            if (doB) {
                f32x4 b0 = {};
                b0 = __builtin_amdgcn_mfma_f32_16x16x32_bf16(ak0, aqB[0], b0, 0, 0, 0);
                b0 = __builtin_amdgcn_mfma_f32_16x16x32_bf16(ak1, aqB[1], b0, 0, 0, 0);
                sB[f] = b0;
            }
        }
        __builtin_amdgcn_s_setprio(0);

        if (t == tA) APPLYMASK(sA, qrowA, t * 64);
        SOFTMAX_PV(cur, sA, mA, lAc, oA);
        if (doB) {
            if (t == tB) APPLYMASK(sB, qrowB, t * 64);
            SOFTMAX_PV(cur, sB, mB, lBc, oB);
        }

        // ---- pipeline tail of step: readers done -> restage freed buffer ->
        // wait only for the OLDEST stage (t+1); t+2's loads stay in flight.
        asm volatile("s_barrier" ::: "memory");
        if (t + 2 < nsteps) {
            STAGE(cur, t + 2);
            asm volatile("s_waitcnt vmcnt(4)" ::: "memory");
        } else {
            asm volatile("s_waitcnt vmcnt(0)" ::: "memory");
        }
        asm volatile("s_barrier" ::: "memory");
    }

    // epilogue: broadcast l to o-rows, normalize, write both q-tiles
    float lvA[4], lvB[4];
    #pragma unroll
    for (int r = 0; r < 4; r++) {
        lvA[r] = __shfl(lAc, rhi * 4 + r);
        lvB[r] = __shfl(lBc, rhi * 4 + r);
    }
    #pragma unroll
    for (int r = 0; r < 4; r++) {
        float invA = 1.f / lvA[r];
        float invB = 1.f / lvB[r];
        long qrA = (long)tA * 64 + wid * 16 + rhi * 4 + r;
        long qrB = (long)tB * 64 + wid * 16 + rhi * 4 + r;
        #pragma unroll
        for (int fd = 0; fd < 4; fd++) {
            int d = fd * 16 + rlo;
            attout[((long)b * T_ + qrA) * E_ + h * DH_ + d] = (__bf16)(oA[fd][r] * invA);
            attout[((long)b * T_ + qrB) * E_ + h * DH_ + d] = (__bf16)(oB[fd][r] * invB);
        }
    }
}

// ---------------------------------------------------------------- launcher
extern "C" void kernel_launch(void* const* d_in, const int* in_sizes, int n_in,
                              void* d_out, int out_size, void* d_ws, size_t ws_size,
                              hipStream_t stream) {
    const float* x  = (const float*)d_in[0];
    const float* Wq = (const float*)d_in[1];
    const float* Wk = (const float*)d_in[2];
    const float* Wv = (const float*)d_in[3];
    const float* Wp = (const float*)d_in[4];
    const float* bp = (const float*)d_in[5];

    char* ws = (char*)d_ws;
    const long SZ_XE = (long)B_ * T_ * E_ * 2;      // 16 MB (bf16 [B*T][E])
    __bf16* xb   = (__bf16*)(ws);                   // x bf16; REUSED as attout after QKV
    __bf16* qb   = (__bf16*)(ws + SZ_XE);
    __bf16* kb   = (__bf16*)(ws + 2 * SZ_XE);
    __bf16* vt   = (__bf16*)(ws + 3 * SZ_XE);       // V^T: [B*H][DH][T]
    __bf16* wcat = (__bf16*)(ws + 4 * SZ_XE);       // [3072][1024] bf16 (6 MB)
    __bf16* wpb  = (__bf16*)(ws + 4 * SZ_XE + (long)3072 * 1024 * 2);
    __bf16* att  = xb;  // alias: xb dead after QKV GEMM (stream-ordered)

    // casts
    cast_f32_to_bf16<<<8192, 256, 0, stream>>>(x, xb, B_ * T_ * E_);
    cast_wcat<<<12288, 256, 0, stream>>>(Wq, Wk, Wv, wcat);
    cast_f32_to_bf16<<<1024, 256, 0, stream>>>(Wp, wpb, E_ * E_);

    // fused QKV projection: [8192][1024] @ wcat^T -> q/k [bh][t][d], vt [bh][d][t]
    gemm128<3><<<dim3(64, 24), 256, 0, stream>>>(
        xb, wcat, nullptr, nullptr, qb, kb, vt, E_, 3 * E_);

    // causal attention (fused paired q-tiles, counted-vmcnt pipeline)
    attn_kernel<<<dim3(16, B_ * H_), 256, 0, stream>>>(qb, kb, vt, att);

    // output projection + bias (fp32 out)
    gemm128<1><<<dim3(64, 8), 256, 0, stream>>>(
        att, wpb, (float*)d_out, bp, nullptr, nullptr, nullptr, E_, E_);
}

// Round 8
// 158.746 us; speedup vs baseline: 3.1499x; 1.0378x over previous
//
#include <hip/hip_runtime.h>
#include <hip/hip_bf16.h>

// Problem constants
#define B_ 4
#define T_ 2048
#define E_ 1024
#define H_ 16
#define DH_ 64

typedef __bf16 bf16x8 __attribute__((ext_vector_type(8)));
typedef __bf16 bf16x4 __attribute__((ext_vector_type(4)));
typedef float f32x4 __attribute__((ext_vector_type(4)));

#define EXP2F(x) __builtin_amdgcn_exp2f(x)
#define NEG_INF (-__builtin_inff())

// async global->LDS, 16B per lane: lane l writes lds_base + l*16
__device__ __forceinline__ void async_copy16(const __bf16* g, __bf16* l) {
    __builtin_amdgcn_global_load_lds(
        (const __attribute__((address_space(1))) unsigned int*)g,
        (__attribute__((address_space(3))) unsigned int*)l, 16, 0, 0);
}

// ---------------------------------------------------------------- fused casts
// one launch: x (8.4M), Wp (1M), wcat build (3.1M) — all bf16x4 stores
__global__ void cast_all(const float* __restrict__ x,
                         const float* __restrict__ Wq, const float* __restrict__ Wk,
                         const float* __restrict__ Wv, const float* __restrict__ Wp,
                         __bf16* __restrict__ xb, __bf16* __restrict__ wcat,
                         __bf16* __restrict__ wpb) {
    int tid = blockIdx.x * blockDim.x + threadIdx.x;   // grid covers 2,097,152
    {
        int i = tid * 4;                                // x: B*T*E = 8,388,608
        float4 f = *reinterpret_cast<const float4*>(x + i);
        bf16x4 o = { (__bf16)f.x, (__bf16)f.y, (__bf16)f.z, (__bf16)f.w };
        *reinterpret_cast<bf16x4*>(xb + i) = o;
    }
    if (tid < 262144) {                                 // Wp: 1,048,576
        int i = tid * 4;
        float4 f = *reinterpret_cast<const float4*>(Wp + i);
        bf16x4 o = { (__bf16)f.x, (__bf16)f.y, (__bf16)f.z, (__bf16)f.w };
        *reinterpret_cast<bf16x4*>(wpb + i) = o;
    }
    if (tid < 786432) {                                 // wcat: 3072*1024
        int i = tid * 4;
        int e = i & (E_ - 1);                           // 4 consecutive e
        int n = i >> 10;
        int rem = n & 1023, h = rem >> 6, d = rem & 63;
        const float* src = (n < 1024) ? Wq : (n < 2048 ? Wk : Wv);
        const float* sp = src + ((long)((h << 10) + e)) * DH_ + d;
        bf16x4 o = { (__bf16)sp[0], (__bf16)sp[DH_], (__bf16)sp[2 * DH_], (__bf16)sp[3 * DH_] };
        *reinterpret_cast<bf16x4*>(wcat + i) = o;
    }
}

// ---------------------------------------------------------------- GEMM v2 (C = A * Bt^T)
// 128x128 tile, BK=64, 4 waves (2x2), global_load_lds staging (pre-swizzled src).
// MODE 1: C[m][N] f32 + bias.   MODE 3: QKV epilogue -> q/k [bh][t][d], vt [bh][d][t].
template<int MODE>
__global__ __launch_bounds__(256, 3) void gemm128(
    const __bf16* __restrict__ A, const __bf16* __restrict__ Bt,
    float* __restrict__ Cf, const float* __restrict__ bias,
    __bf16* __restrict__ oq, __bf16* __restrict__ ok, __bf16* __restrict__ ovt,
    int K, int N) {

    __shared__ __bf16 As[128][64];
    __shared__ __bf16 Bs[128][64];

    int tid = threadIdx.x, lane = tid & 63, wid = tid >> 6;
    int wr = wid >> 1, wc = wid & 1;
    int rlo = lane & 15, rhi = lane >> 4;
    int l8 = lane >> 3, c = lane & 7;

    const __bf16* Ab = A + (long)blockIdx.x * 128 * K;
    const __bf16* Bb = Bt + (long)blockIdx.y * 128 * K;

    f32x4 acc[4][4] = {};

    for (int k0 = 0; k0 < K; k0 += 64) {
        #pragma unroll
        for (int p = 0; p < 4; p++) {
            int gr = p * 32 + wid * 8 + l8;
            int sc = c ^ (gr & 7);
            async_copy16(Ab + (long)gr * K + k0 + sc * 8, &As[p * 32 + wid * 8][0]);
        }
        #pragma unroll
        for (int p = 0; p < 4; p++) {
            int gr = p * 32 + wid * 8 + l8;
            int sc = c ^ (gr & 7);
            async_copy16(Bb + (long)gr * K + k0 + sc * 8, &Bs[p * 32 + wid * 8][0]);
        }
        __syncthreads();   // drains vmcnt -> tiles ready

        #pragma unroll
        for (int kk = 0; kk < 2; kk++) {
            bf16x8 af[4], bfr[4];
            #pragma unroll
            for (int mi = 0; mi < 4; mi++) {
                int r = wr * 64 + mi * 16 + rlo;
                af[mi] = *reinterpret_cast<const bf16x8*>(
                    &As[r][((kk * 4 + rhi) ^ (r & 7)) * 8]);
            }
            #pragma unroll
            for (int ni = 0; ni < 4; ni++) {
                int r = wc * 64 + ni * 16 + rlo;
                bfr[ni] = *reinterpret_cast<const bf16x8*>(
                    &Bs[r][((kk * 4 + rhi) ^ (r & 7)) * 8]);
            }
            #pragma unroll
            for (int mi = 0; mi < 4; mi++)
                #pragma unroll
                for (int ni = 0; ni < 4; ni++)
                    acc[mi][ni] = __builtin_amdgcn_mfma_f32_16x16x32_bf16(
                        af[mi], bfr[ni], acc[mi][ni], 0, 0, 0);
        }
        __syncthreads();   // WAR before next stage
    }

    long m0 = (long)blockIdx.x * 128 + wr * 64;
    int n0 = blockIdx.y * 128 + wc * 64;

    if constexpr (MODE == 1) {
        #pragma unroll
        for (int mi = 0; mi < 4; mi++) {
            #pragma unroll
            for (int ni = 0; ni < 4; ni++) {
                int cn = n0 + ni * 16 + rlo;
                #pragma unroll
                for (int r = 0; r < 4; r++) {
                    long rm = m0 + mi * 16 + rhi * 4 + r;
                    Cf[rm * N + cn] = acc[mi][ni][r] + bias[cn];
                }
            }
        }
    } else {
        int type = blockIdx.y >> 3;   // 0=q, 1=k, 2=v (N=3072, 8 n-blocks each)
        #pragma unroll
        for (int mi = 0; mi < 4; mi++) {
            long m_ = m0 + mi * 16 + rhi * 4;
            int b = (int)(m_ >> 11);
            int t0 = (int)(m_ & 2047);
            #pragma unroll
            for (int ni = 0; ni < 4; ni++) {
                int n = n0 + ni * 16 + rlo;
                int rem = n & 1023, h = rem >> 6, d = rem & 63;
                long bh = b * 16 + h;
                if (type == 2) {
                    bf16x4 o = { (__bf16)acc[mi][ni][0], (__bf16)acc[mi][ni][1],
                                 (__bf16)acc[mi][ni][2], (__bf16)acc[mi][ni][3] };
                    *reinterpret_cast<bf16x4*>(ovt + (bh * 64 + d) * 2048 + t0) = o;
                } else {
                    __bf16* dst = (type ? ok : oq) + bh * 2048 * 64;
                    #pragma unroll
                    for (int r = 0; r < 4; r++)
                        dst[(long)(t0 + r) * 64 + d] = (__bf16)acc[mi][ni][r];
                }
            }
        }
    }
}

// ---------------------------------------------------------------- attention
// grid (16, 64); 256 threads = 4 waves. fid remapped so each (b,h)'s 16
// blocks land on ONE XCD. Block handles q-tiles {31-p, p} fused over one KV
// sweep; merged PROCESS (shared K-frags). 2-deep counted-vmcnt pipeline.
// Softmax: lane-local partial l (reduced once in epilogue); pm cross-lane
// reduce only on the (rare) rescale path — defer-max vote uses local maxima.
__global__ __launch_bounds__(256, 4) void attn_kernel(
    const __bf16* __restrict__ q, const __bf16* __restrict__ k,
    const __bf16* __restrict__ vt, __bf16* __restrict__ attout) {

    __shared__ __bf16 Ks[2][64][64];
    __shared__ __bf16 Vs[2][64][64];
    __shared__ __bf16 Pl[4][16][64];

    int tid = threadIdx.x, lane = tid & 63, wid = tid >> 6;
    int rlo = lane & 15, rhi = lane >> 4;

    int fid = blockIdx.y * 16 + blockIdx.x;
    int xcd = fid & 7, slot = fid >> 3;     // round-robin XCD assumption (perf-only)
    int bh = xcd * 8 + (slot >> 4);         // 8 bh per XCD
    int p = slot & 15;
    int tA = 31 - p, tB = p;                // q-tile indices (64-row tiles)

    int b = bh >> 4, h = bh & 15;
    const __bf16* qb = q + (long)bh * T_ * DH_;
    const __bf16* kb = k + (long)bh * T_ * DH_;
    const __bf16* vtb = vt + (long)bh * T_ * DH_;   // [DH][T]

    const float SCL = 0.125f * 1.44269504088896340736f;  // 1/8 * log2(e)

    // staging geometry (pre-swizzled global source, linear LDS dest)
    int srow = wid * 16 + (lane >> 3);
    int sc0 = (lane & 7) ^ (srow & 7);

    // Q fragments for both tiles (rlo = q row; rhi = d-chunk)
    bf16x8 aqA[2], aqB[2];
    {
        long qrA = (long)tA * 64 + wid * 16 + rlo;
        aqA[0] = *reinterpret_cast<const bf16x8*>(qb + qrA * DH_ + 8 * rhi);
        aqA[1] = *reinterpret_cast<const bf16x8*>(qb + qrA * DH_ + 32 + 8 * rhi);
        long qrB = (long)tB * 64 + wid * 16 + rlo;
        aqB[0] = *reinterpret_cast<const bf16x8*>(qb + qrB * DH_ + 8 * rhi);
        aqB[1] = *reinterpret_cast<const bf16x8*>(qb + qrB * DH_ + 32 + 8 * rhi);
    }

    float mA = NEG_INF, lAc = 0.f, mB = NEG_INF, lBc = 0.f;
    f32x4 oA[4] = {}, oB[4] = {};

    auto STAGE = [&](int bs, int t) {
        const __bf16* ksrc = kb + (long)(t * 64 + srow) * DH_ + sc0 * 8;
        async_copy16(ksrc,           &Ks[bs][wid * 16][0]);
        async_copy16(ksrc + 8 * DH_, &Ks[bs][wid * 16 + 8][0]);
        const __bf16* vsrc = vtb + (long)srow * T_ + t * 64 + sc0 * 8;
        async_copy16(vsrc,           &Vs[bs][wid * 16][0]);
        async_copy16(vsrc + 8 * T_,  &Vs[bs][wid * 16 + 8][0]);
    };

    auto APPLYMASK = [&](f32x4* s, int qrow, int kt0) {
        int kbase = kt0 + rhi * 4;
        #pragma unroll
        for (int f = 0; f < 4; f++)
            #pragma unroll
            for (int r = 0; r < 4; r++)
                if (kbase + f * 16 + r > qrow) s[f][r] = NEG_INF;
    };

    // online softmax on raw s; lane-local partial l; pm reduce only on rescale
    auto SOFTMAX_PV = [&](int bs, f32x4* s, float& m_, float& l_, f32x4* o) {
        // lane-local max over this lane's 16 keys
        f32x4 mx;
        #pragma unroll
        for (int r = 0; r < 4; r++)
            mx[r] = fmaxf(fmaxf(s[0][r], s[1][r]), fmaxf(s[2][r], s[3][r]));
        float pml = fmaxf(fmaxf(mx[0], mx[1]), fmaxf(mx[2], mx[3]));
        float pms = pml * SCL;   // scaled-domain local max

        // defer-max vote on LOCAL maxima: if every lane's 16-key max is within
        // m+8, the row max is too, and m stays row-uniform. Rescale path (rare)
        // does the true cross-rhi row reduce.
        bool need = !__all(pms <= m_ + 8.f);
        if (need) {
            float pr = fmaxf(pms, __shfl_xor(pms, 16));
            pr = fmaxf(pr, __shfl_xor(pr, 32));
            float nm = fmaxf(m_, pr);
            float so = EXP2F(m_ - nm);
            m_ = nm;
            l_ *= so;
            float sov[4];
            #pragma unroll
            for (int r = 0; r < 4; r++) sov[r] = __shfl(so, rhi * 4 + r);
            #pragma unroll
            for (int fd = 0; fd < 4; fd++)
                #pragma unroll
                for (int r = 0; r < 4; r++)
                    o[fd][r] *= sov[r];
        }

        // p = exp2(s*SCL - m) via fma; accumulate lane-local partial l
        float rsum = 0.f;
        #pragma unroll
        for (int f = 0; f < 4; f++)
            #pragma unroll
            for (int r = 0; r < 4; r++) {
                float pv = EXP2F(fmaf(s[f][r], SCL, -m_));
                s[f][r] = pv;
                rsum += pv;
            }
        l_ += rsum;   // partial: reduced across rhi groups in epilogue

        // P pack: 4 consecutive keys -> b64 swizzled write
        #pragma unroll
        for (int f = 0; f < 4; f++) {
            bf16x4 pw = { (__bf16)s[f][0], (__bf16)s[f][1],
                          (__bf16)s[f][2], (__bf16)s[f][3] };
            int keyb = f * 16 + rhi * 4;
            int c16 = keyb >> 3, sub = (keyb >> 2) & 1;
            *reinterpret_cast<bf16x4*>(
                &Pl[wid][rlo][((c16 ^ (rlo & 7)) << 3) + (sub << 2)]) = pw;
        }

        // O += P V
        __builtin_amdgcn_s_setprio(1);
        #pragma unroll
        for (int kk = 0; kk < 2; kk++) {
            int ck = kk * 4 + rhi;
            bf16x8 ap = *reinterpret_cast<const bf16x8*>(&Pl[wid][rlo][(ck ^ (rlo & 7)) * 8]);
            #pragma unroll
            for (int fd = 0; fd < 4; fd++) {
                int vr = fd * 16 + rlo;
                bf16x8 bv = *reinterpret_cast<const bf16x8*>(
                    &Vs[bs][vr][(ck ^ (vr & 7)) * 8]);
                o[fd] = __builtin_amdgcn_mfma_f32_16x16x32_bf16(ap, bv, o[fd], 0, 0, 0);
            }
        }
        __builtin_amdgcn_s_setprio(0);
    };

    int qrowA = tA * 64 + wid * 16 + rlo;
    int qrowB = tB * 64 + wid * 16 + rlo;

    int nsteps = tA + 1;   // >= 17

    // prologue: 2-deep prefetch; wait for tile 0 only (vmcnt covers Q loads too)
    STAGE(0, 0);
    STAGE(1, 1);
    asm volatile("s_waitcnt vmcnt(4)" ::: "memory");
    asm volatile("s_barrier" ::: "memory");

    for (int t = 0; t < nsteps; ++t) {
        int cur = t & 1;
        bool doB = (t <= tB);

        // QK^T for both q-tiles, K-fragments read ONCE
        f32x4 sA[4], sB[4];
        __builtin_amdgcn_s_setprio(1);
        #pragma unroll
        for (int f = 0; f < 4; f++) {
            int kr = f * 16 + rlo;
            bf16x8 ak0 = *reinterpret_cast<const bf16x8*>(
                &Ks[cur][kr][((0 + rhi) ^ (kr & 7)) * 8]);
            bf16x8 ak1 = *reinterpret_cast<const bf16x8*>(
                &Ks[cur][kr][((4 + rhi) ^ (kr & 7)) * 8]);
            f32x4 a0 = {};
            a0 = __builtin_amdgcn_mfma_f32_16x16x32_bf16(ak0, aqA[0], a0, 0, 0, 0);
            a0 = __builtin_amdgcn_mfma_f32_16x16x32_bf16(ak1, aqA[1], a0, 0, 0, 0);
            sA[f] = a0;
            if (doB) {
                f32x4 b0 = {};
                b0 = __builtin_amdgcn_mfma_f32_16x16x32_bf16(ak0, aqB[0], b0, 0, 0, 0);
                b0 = __builtin_amdgcn_mfma_f32_16x16x32_bf16(ak1, aqB[1], b0, 0, 0, 0);
                sB[f] = b0;
            }
        }
        __builtin_amdgcn_s_setprio(0);

        if (t == tA) APPLYMASK(sA, qrowA, t * 64);
        SOFTMAX_PV(cur, sA, mA, lAc, oA);
        if (doB) {
            if (t == tB) APPLYMASK(sB, qrowB, t * 64);
            SOFTMAX_PV(cur, sB, mB, lBc, oB);
        }

        // ---- pipeline tail: readers done -> restage freed buffer ->
        // wait only for the OLDEST stage (t+1); t+2's loads stay in flight.
        asm volatile("s_barrier" ::: "memory");
        if (t + 2 < nsteps) {
            STAGE(cur, t + 2);
            asm volatile("s_waitcnt vmcnt(4)" ::: "memory");
        } else {
            asm volatile("s_waitcnt vmcnt(0)" ::: "memory");
        }
        asm volatile("s_barrier" ::: "memory");
    }

    // epilogue: complete the row-sum of l (partials live per rhi group),
    // broadcast to o-rows, normalize, write both q-tiles
    lAc += __shfl_xor(lAc, 16);
    lAc += __shfl_xor(lAc, 32);
    lBc += __shfl_xor(lBc, 16);
    lBc += __shfl_xor(lBc, 32);

    float lvA[4], lvB[4];
    #pragma unroll
    for (int r = 0; r < 4; r++) {
        lvA[r] = __shfl(lAc, rhi * 4 + r);
        lvB[r] = __shfl(lBc, rhi * 4 + r);
    }
    #pragma unroll
    for (int r = 0; r < 4; r++) {
        float invA = 1.f / lvA[r];
        float invB = 1.f / lvB[r];
        long qrA = (long)tA * 64 + wid * 16 + rhi * 4 + r;
        long qrB = (long)tB * 64 + wid * 16 + rhi * 4 + r;
        #pragma unroll
        for (int fd = 0; fd < 4; fd++) {
            int d = fd * 16 + rlo;
            attout[((long)b * T_ + qrA) * E_ + h * DH_ + d] = (__bf16)(oA[fd][r] * invA);
            attout[((long)b * T_ + qrB) * E_ + h * DH_ + d] = (__bf16)(oB[fd][r] * invB);
        }
    }
}

// ---------------------------------------------------------------- launcher
extern "C" void kernel_launch(void* const* d_in, const int* in_sizes, int n_in,
                              void* d_out, int out_size, void* d_ws, size_t ws_size,
                              hipStream_t stream) {
    const float* x  = (const float*)d_in[0];
    const float* Wq = (const float*)d_in[1];
    const float* Wk = (const float*)d_in[2];
    const float* Wv = (const float*)d_in[3];
    const float* Wp = (const float*)d_in[4];
    const float* bp = (const float*)d_in[5];

    char* ws = (char*)d_ws;
    const long SZ_XE = (long)B_ * T_ * E_ * 2;      // 16 MB (bf16 [B*T][E])
    __bf16* xb   = (__bf16*)(ws);                   // x bf16; REUSED as attout after QKV
    __bf16* qb   = (__bf16*)(ws + SZ_XE);
    __bf16* kb   = (__bf16*)(ws + 2 * SZ_XE);
    __bf16* vt   = (__bf16*)(ws + 3 * SZ_XE);       // V^T: [B*H][DH][T]
    __bf16* wcat = (__bf16*)(ws + 4 * SZ_XE);       // [3072][1024] bf16 (6 MB)
    __bf16* wpb  = (__bf16*)(ws + 4 * SZ_XE + (long)3072 * 1024 * 2);
    __bf16* att  = xb;  // alias: xb dead after QKV GEMM (stream-ordered)

    // fused casts (x, Wp, wcat in one launch)
    cast_all<<<8192, 256, 0, stream>>>(x, Wq, Wk, Wv, Wp, xb, wcat, wpb);

    // fused QKV projection: [8192][1024] @ wcat^T -> q/k [bh][t][d], vt [bh][d][t]
    gemm128<3><<<dim3(64, 24), 256, 0, stream>>>(
        xb, wcat, nullptr, nullptr, qb, kb, vt, E_, 3 * E_);

    // causal attention (fused paired q-tiles, counted-vmcnt pipeline)
    attn_kernel<<<dim3(16, B_ * H_), 256, 0, stream>>>(qb, kb, vt, att);

    // output projection + bias (fp32 out)
    gemm128<1><<<dim3(64, 8), 256, 0, stream>>>(
        att, wpb, (float*)d_out, bp, nullptr, nullptr, nullptr, E_, E_);
}